// Round 11
// baseline (947.206 us; speedup 1.0000x reference)
//
#include <hip/hip_runtime.h>

#define H_ 4
#define O_ 32
#define HO 128
#define M_ 128
#define M2 256
#define D_ 16
#define B_ 1024
#define JIT 1e-4f

typedef unsigned short ushort_t;
typedef __bf16 v8bf __attribute__((ext_vector_type(8)));
typedef float v16f __attribute__((ext_vector_type(16)));
typedef unsigned short v8us __attribute__((ext_vector_type(8)));
typedef unsigned short v4us __attribute__((ext_vector_type(4)));

__device__ inline void splitbf(float v, ushort_t& hb, ushort_t& lb) {
    unsigned int u = __float_as_uint(v);
    hb = (ushort_t)(u >> 16);
    float hf = __uint_as_float((unsigned int)hb << 16);
    float r = v - hf;
    lb = (ushort_t)(__float_as_uint(r) >> 16);
}
__device__ inline float bf2f(ushort_t u) { return __uint_as_float((unsigned int)u << 16); }

// ---------------------------------------------------------------------------
// merged preprocessing + kuu2: blocks 0-127 scale_z AND kuu2 for their pair
// (zs already in LDS); 128-143 scale_x; 144 SF2
__global__ __launch_bounds__(256) void k_prekuu2(const float* __restrict__ theta,
                                                 const float* __restrict__ x,
                                                 const float* __restrict__ z,
                                                 const float* __restrict__ z_old,
                                                 float* __restrict__ SF2,
                                                 float* __restrict__ XS, float* __restrict__ XN,
                                                 float* __restrict__ ZS, float* __restrict__ ZN,
                                                 float* __restrict__ K2) {
    int bb = blockIdx.x, t = threadIdx.x;
    __shared__ float zs[M2][D_];
    __shared__ float zn[M2];
    __shared__ float ls[D_];
    if (bb == 144) {
        if (t < H_) SF2[t] = __expf(theta[t * (D_ + 1)]);
        return;
    }
    if (bb >= 128) {
        int j = (bb - 128) * 256 + t;
        int h = j >> 10, b = j & 1023;
        if (t < D_) ls[t] = __expf(-theta[h * (D_ + 1) + 1 + t]);
        __syncthreads();
        float s = 0.f;
#pragma unroll
        for (int d = 0; d < D_; d++) {
            float v = x[b * D_ + d] * ls[d];
            XS[(long)j * D_ + d] = v;
            s += v * v;
        }
        XN[j] = s;
        return;
    }
    // scale_z + kuu2
    int pair = bb, h = pair >> 5, o = pair & 31, i = t;
    if (t < D_) ls[t] = __expf(-theta[h * (D_ + 1) + 1 + t]);
    __syncthreads();
    const float* src = (i < M_) ? (z_old + ((long)o * M_ + i) * D_)
                                : (z + ((long)o * M_ + (i - M_)) * D_);
    float s = 0.f;
#pragma unroll
    for (int d = 0; d < D_; d++) {
        float v = src[d] * ls[d];
        zs[i][d] = v;
        ZS[((long)pair * M2 + i) * D_ + d] = v;
        s += v * v;
    }
    zn[i] = s;
    ZN[pair * M2 + i] = s;
    __syncthreads();
    float sf2 = __expf(theta[h * (D_ + 1)]);
    float my[D_];
#pragma unroll
    for (int d = 0; d < D_; d++) my[d] = zs[i][d];
    float myn = zn[i];
    for (int q = 0; q < M2; q++) {
        float dot = 0.f;
#pragma unroll
        for (int d = 0; d < D_; d++) dot += zs[q][d] * my[d];
        float d2 = fmaxf(zn[q] + myn - 2.f * dot, 0.f);
        float v = sf2 * __expf(-0.5f * d2);
        if (q == i) v += JIT;
        K2[(long)pair * M2 * M2 + (long)q * M2 + i] = v;
    }
}

// fused chol(128) + triangular inverse, register/wave-synchronous core.
// Diag 32x32 factor: one wave, columns in registers, LDS broadcast, no barriers.
__global__ __launch_bounds__(256) void k_choltri(const float* __restrict__ src, long sps, int ldsrc,
                                                 float* __restrict__ Li) {
    int pair = blockIdx.x, t = threadIdx.x;
    __shared__ float Ap[M_ * (M_ + 1) / 2];  // packed lower L (and input A)
    __shared__ float colb[32];
    __shared__ float invd[128];              // 1/L[i][i]
    __shared__ float Wd[2][64][66];
    __shared__ float Tt[64][66];
    const float* S = src + (long)pair * sps;
    for (int e = t; e < M_ * (M_ + 1) / 2; e += 256) {
        int i = (int)((sqrtf(8.f * e + 1.f) - 1.f) * 0.5f);
        while ((i + 1) * (i + 2) / 2 <= e) i++;
        while (i * (i + 1) / 2 > e) i--;
        int j = e - i * (i + 1) / 2;
        Ap[e] = S[(long)i * ldsrc + j];
    }
    __syncthreads();

    for (int kb = 0; kb < 4; kb++) {
        int c0 = kb * 32;
        // --- diag factor: wave0 lanes 0..31, column l in registers
        if (t < 32) {
            int l = t;
            float c[32];
#pragma unroll
            for (int i = 0; i < 32; i++) {
                int gi = c0 + i;
                c[i] = (i >= l) ? Ap[gi * (gi + 1) / 2 + c0 + l] : 0.f;
            }
            for (int k = 0; k < 32; k++) {
                if (l == k) {
#pragma unroll
                    for (int i = 0; i < 32; i++) colb[i] = c[i];
                }
                __builtin_amdgcn_wave_barrier();
                float rd = 1.f / colb[k];
                float f = colb[l] * rd;
                if (l > k) {
#pragma unroll
                    for (int i = 0; i < 32; i++)
                        if (i >= l) c[i] -= colb[i] * f;
                }
                __builtin_amdgcn_wave_barrier();
            }
            float r = rsqrtf(c[l]);
            invd[c0 + l] = 1.f / (c[l] * r);
#pragma unroll
            for (int i = 0; i < 32; i++)
                if (i >= l) {
                    int gi = c0 + i;
                    Ap[gi * (gi + 1) / 2 + c0 + l] = c[i] * r;
                }
        }
        __syncthreads();

        int R = M_ - c0 - 32;
        if (R > 0) {
            // --- trsm: one row per thread, register solve against scaled L11
            if (t < R) {
                int gi = c0 + 32 + t;
                int base = gi * (gi + 1) / 2 + c0;
                float xr[32];
#pragma unroll
                for (int j = 0; j < 32; j++) xr[j] = Ap[base + j];
#pragma unroll
                for (int q = 0; q < 32; q++) {
                    float xq = xr[q] * invd[c0 + q];
                    xr[q] = xq;
#pragma unroll
                    for (int j = q + 1; j < 32; j++)
                        xr[j] -= xq * Ap[(c0 + j) * (c0 + j + 1) / 2 + c0 + q];
                }
#pragma unroll
                for (int j = 0; j < 32; j++) Ap[base + j] = xr[j];
            }
            __syncthreads();
            // --- syrk trailing update, 4x4 register tiles over lower triangle
            int nb = R >> 2;
            int ntile = nb * (nb + 1) / 2;
            for (int tp = t; tp < ntile; tp += 256) {
                int bi = (int)((sqrtf(8.f * tp + 1.f) - 1.f) * 0.5f);
                while ((bi + 1) * (bi + 2) / 2 <= tp) bi++;
                while (bi * (bi + 1) / 2 > tp) bi--;
                int bj = tp - bi * (bi + 1) / 2;
                int i0 = c0 + 32 + bi * 4, j0 = c0 + 32 + bj * 4;
                float acc[4][4] = {};
                for (int k = 0; k < 32; k++) {
                    float a[4], b[4];
#pragma unroll
                    for (int q = 0; q < 4; q++) a[q] = Ap[(i0 + q) * (i0 + q + 1) / 2 + c0 + k];
#pragma unroll
                    for (int r = 0; r < 4; r++) b[r] = Ap[(j0 + r) * (j0 + r + 1) / 2 + c0 + k];
#pragma unroll
                    for (int q = 0; q < 4; q++)
#pragma unroll
                        for (int r = 0; r < 4; r++) acc[q][r] += a[q] * b[r];
                }
#pragma unroll
                for (int q = 0; q < 4; q++)
#pragma unroll
                    for (int r = 0; r < 4; r++) {
                        int gi = i0 + q, gj = j0 + r;
                        if (gj <= gi) Ap[gi * (gi + 1) / 2 + gj] -= acc[q][r];
                    }
            }
            __syncthreads();
        }
    }

    // ---- trinv: register-column serial solve per thread (2 diag blocks)
    if (t < 128) {
        int g = t >> 6, c = t & 63;
        int b0 = g * 64;
        float wv[64];
#pragma unroll
        for (int i = 0; i < 64; i++) {
            float acc = (i == c) ? 1.f : 0.f;
#pragma unroll
            for (int j = 0; j < i; j++) {
                int gi = b0 + i;
                acc -= Ap[gi * (gi + 1) / 2 + b0 + j] * wv[j];
            }
            wv[i] = acc * invd[b0 + i];
        }
#pragma unroll
        for (int i = 0; i < 64; i++) Wd[g][i][c] = wv[i];
    }
    __syncthreads();

    // Tt = LB @ Wd0   (LB = L[64..127][0..63] read from packed Ap)
    long b1 = (long)pair * 16384;
    int ti = t >> 4, tj = t & 15;
    float acc[4][4] = {};
    for (int kk = 0; kk < 64; kk++) {
        float a[4], b[4];
#pragma unroll
        for (int q = 0; q < 4; q++) {
            int gi = 64 + ti * 4 + q;
            a[q] = Ap[gi * (gi + 1) / 2 + kk];
        }
#pragma unroll
        for (int r = 0; r < 4; r++) b[r] = Wd[0][kk][tj * 4 + r];
#pragma unroll
        for (int q = 0; q < 4; q++)
#pragma unroll
            for (int r = 0; r < 4; r++) acc[q][r] += a[q] * b[r];
    }
#pragma unroll
    for (int q = 0; q < 4; q++)
#pragma unroll
        for (int r = 0; r < 4; r++) Tt[ti * 4 + q][tj * 4 + r] = acc[q][r];
    __syncthreads();
    // BL of Linv = -Wd1 @ Tt
    float xo[4][4] = {};
    for (int kk = 0; kk < 64; kk++) {
        float a[4], b[4];
#pragma unroll
        for (int q = 0; q < 4; q++) a[q] = Wd[1][ti * 4 + q][kk];
#pragma unroll
        for (int r = 0; r < 4; r++) b[r] = Tt[kk][tj * 4 + r];
#pragma unroll
        for (int q = 0; q < 4; q++)
#pragma unroll
            for (int r = 0; r < 4; r++) xo[q][r] -= a[q] * b[r];
    }
#pragma unroll
    for (int q = 0; q < 4; q++)
#pragma unroll
        for (int r = 0; r < 4; r++)
            Li[b1 + (long)(64 + ti * 4 + q) * 128 + tj * 4 + r] = xo[q][r];
    for (int e = t; e < 4096; e += 256) {
        int i = e >> 6, j = e & 63;
        Li[b1 + (long)i * 128 + j] = Wd[0][i][j];
        Li[b1 + (long)(64 + i) * 128 + 64 + j] = Wd[1][i][j];
        Li[b1 + (long)i * 128 + 64 + j] = 0.f;
    }
}

// merged A1/A3: y=0: A1 = Linv1 @ kuf(KUU2 TR); y=1: A3 = Linv1 @ L_old
__global__ __launch_bounds__(256) void k_a1a3(const float* __restrict__ Linv1,
                                              const float* __restrict__ KUU2,
                                              const float* __restrict__ L_old,
                                              float* __restrict__ A1, float* __restrict__ A3) {
    int pair = blockIdx.x, y = blockIdx.y, o = pair & 31;
    const float* Ap = Linv1 + (long)pair * 16384;
    const float* Bp = y ? (L_old + (long)o * 16384) : (KUU2 + (long)pair * 65536 + 128);
    int ldb = y ? 128 : 256;
    float* Cp = (y ? A3 : A1) + (long)pair * 16384;
    int t = threadIdx.x, tx = t & 15, ty = t >> 4;
    __shared__ float As[16][132], Bs[16][132];
    float acc[8][8] = {};
    for (int kt = 0; kt < M_; kt += 16) {
#pragma unroll
        for (int q = 0; q < 8; q++) {
            int e = q * 256 + t;
            int m = e >> 4, kk = e & 15;
            As[kk][m] = Ap[(long)m * 128 + kt + kk];
            int kk2 = e >> 7, n = e & 127;
            Bs[kk2][n] = Bp[(long)(kt + kk2) * ldb + n];
        }
        __syncthreads();
#pragma unroll
        for (int kk = 0; kk < 16; kk++) {
            float a[8], b[8];
#pragma unroll
            for (int q = 0; q < 8; q++) { a[q] = As[kk][ty + 16 * q]; b[q] = Bs[kk][tx + 16 * q]; }
#pragma unroll
            for (int q = 0; q < 8; q++)
#pragma unroll
                for (int r = 0; r < 8; r++) acc[q][r] += a[q] * b[r];
        }
        __syncthreads();
    }
#pragma unroll
    for (int q = 0; q < 8; q++)
#pragma unroll
        for (int r = 0; r < 8; r++)
            Cp[(long)(ty + 16 * q) * 128 + tx + 16 * r] = acc[q][r];
}

// merged BLW/Schur: y=0: BLW = A1^T @ A3; y=1: KUU2_BR -= A1^T @ A1
__global__ __launch_bounds__(256) void k_blwschur(const float* __restrict__ A1,
                                                  const float* __restrict__ A3,
                                                  float* __restrict__ BLW,
                                                  float* __restrict__ KUU2) {
    int pair = blockIdx.x, y = blockIdx.y;
    const float* Ap = A1 + (long)pair * 16384;
    const float* Bp = (y ? A1 : A3) + (long)pair * 16384;
    float* Cp;
    int ldc;
    if (y) { Cp = KUU2 + (long)pair * 65536 + 128L * 256 + 128; ldc = 256; }
    else   { Cp = BLW + (long)pair * 16384; ldc = 128; }
    int t = threadIdx.x, tx = t & 15, ty = t >> 4;
    __shared__ float As[16][132], Bs[16][132];
    float acc[8][8] = {};
    for (int kt = 0; kt < M_; kt += 16) {
#pragma unroll
        for (int q = 0; q < 8; q++) {
            int e = q * 256 + t;
            int kk = e >> 7, m = e & 127;
            As[kk][m] = Ap[(long)(kt + kk) * 128 + m];
            Bs[kk][m] = Bp[(long)(kt + kk) * 128 + m];
        }
        __syncthreads();
#pragma unroll
        for (int kk = 0; kk < 16; kk++) {
            float a[8], b[8];
#pragma unroll
            for (int q = 0; q < 8; q++) { a[q] = As[kk][ty + 16 * q]; b[q] = Bs[kk][tx + 16 * q]; }
#pragma unroll
            for (int q = 0; q < 8; q++)
#pragma unroll
                for (int r = 0; r < 8; r++) acc[q][r] += a[q] * b[r];
        }
        __syncthreads();
    }
#pragma unroll
    for (int q = 0; q < 8; q++)
#pragma unroll
        for (int r = 0; r < 8; r++) {
            long idx = (long)(ty + 16 * q) * ldc + tx + 16 * r;
            if (y) Cp[idx] -= acc[q][r];
            else Cp[idx] = acc[q][r];
        }
}

// a2 = Linv128 * m_old ; m_new = A1^T a2 + u_mean ; write m_joint
__global__ __launch_bounds__(128) void k_stage1vec(const float* __restrict__ Linv128,
                                                   const float* __restrict__ A1,
                                                   const float* __restrict__ m_old,
                                                   const float* __restrict__ u_mean,
                                                   float* __restrict__ MJ) {
    int pair = blockIdx.x, o = pair & 31, t = threadIdx.x;
    __shared__ float mo[128], a2[128];
    mo[t] = m_old[o * 128 + t];
    __syncthreads();
    const float* Lr = Linv128 + (long)pair * 16384 + (long)t * 128;
    float acc = 0.f;
    for (int j = 0; j <= t; j++) acc += Lr[j] * mo[j];
    a2[t] = acc;
    __syncthreads();
    float m = 0.f;
    for (int i = 0; i < 128; i++) m += A1[(long)pair * 16384 + (long)i * 128 + t] * a2[i];
    MJ[pair * 256 + t] = mo[t];
    MJ[pair * 256 + 128 + t] = m + u_mean[o * 128 + t];
}

// generic batched fp32 SGEMM
template <int TA, int TB>
__global__ __launch_bounds__(256) void k_bmm(const float* __restrict__ A, long aSH, long aSO, int lda,
                                             const float* __restrict__ B, long bSH, long bSO, int ldb,
                                             float* __restrict__ C, long cSH, long cSO, int ldc,
                                             int Ksz, float alpha, int accum) {
    int pair = blockIdx.x;
    int h = pair >> 5, o = pair & 31;
    const float* Ap = A + (long)h * aSH + (long)o * aSO;
    const float* Bp = B + (long)h * bSH + (long)o * bSO;
    float* Cp = C + (long)h * cSH + (long)o * cSO;
    int t = threadIdx.x, tx = t & 15, ty = t >> 4;
    __shared__ float As[16][132], Bs[16][132];
    float acc[8][8] = {};
    for (int kt = 0; kt < Ksz; kt += 16) {
#pragma unroll
        for (int q = 0; q < 8; q++) {
            int e = q * 256 + t;
            if (TA) {
                int kk = e >> 7, m = e & 127;
                As[kk][m] = Ap[(long)(kt + kk) * lda + m];
            } else {
                int m = e >> 4, kk = e & 15;
                As[kk][m] = Ap[(long)m * lda + kt + kk];
            }
            if (TB) {
                int n = e >> 4, kk = e & 15;
                Bs[kk][n] = Bp[(long)n * ldb + kt + kk];
            } else {
                int kk = e >> 7, n = e & 127;
                Bs[kk][n] = Bp[(long)(kt + kk) * ldb + n];
            }
        }
        __syncthreads();
#pragma unroll
        for (int kk = 0; kk < 16; kk++) {
            float a[8], b[8];
#pragma unroll
            for (int q = 0; q < 8; q++) { a[q] = As[kk][ty + 16 * q]; b[q] = Bs[kk][tx + 16 * q]; }
#pragma unroll
            for (int q = 0; q < 8; q++)
#pragma unroll
                for (int r = 0; r < 8; r++) acc[q][r] += a[q] * b[r];
        }
        __syncthreads();
    }
#pragma unroll
    for (int q = 0; q < 8; q++)
#pragma unroll
        for (int r = 0; r < 8; r++) {
            long idx = (long)(ty + 16 * q) * ldc + tx + 16 * r;
            float v = alpha * acc[q][r];
            if (accum) v += Cp[idx];
            Cp[idx] = v;
        }
}

// merged split-planes kernel: y=0 -> LINVT from (Linv1,BLi,Linv2); y=1 -> WcT from (L_old,BLW,u_tril)
// NOTE: BLi must NOT alias the WcT output planes (caller places BLi in BIG0).
__global__ __launch_bounds__(256) void k_split2(const float* __restrict__ Linv1,
                                                const float* __restrict__ BLi,
                                                const float* __restrict__ Linv2,
                                                const float* __restrict__ L_old,
                                                const float* __restrict__ BLW,
                                                const float* __restrict__ vec,
                                                ushort_t* __restrict__ LTh, ushort_t* __restrict__ LTl,
                                                ushort_t* __restrict__ WTh, ushort_t* __restrict__ WTl) {
    int pair = blockIdx.x, y = blockIdx.y, o = pair & 31, t = threadIdx.x;
    long b2 = (long)pair * 65536, b1 = (long)pair * 16384;
    int tx = t & 31, ty = t >> 5;
    __shared__ float vs[M_ * (M_ + 1) / 2];
    __shared__ float tile[32][33];
    ushort_t* Th = y ? WTh : LTh;
    ushort_t* Tl = y ? WTl : LTl;
    if (y) {
        for (int e = t; e < M_ * (M_ + 1) / 2; e += 256) vs[e] = vec[(long)o * (M_ * (M_ + 1) / 2) + e];
        __syncthreads();
        for (int e = t; e < 16384; e += 256) {
            int n = e >> 7, k = e & 127;
            float v = (k >= n) ? vs[k * (k + 1) / 2 + n] : 0.f;
            ushort_t hb, lb;
            splitbf(v, hb, lb);
            long a = b2 + (long)(128 + n) * 256 + 128 + k;
            Th[a] = hb;
            Tl[a] = lb;
        }
    }
    for (int e = t; e < 16384; e += 256) {
        int n = e >> 7, k = e & 127;
        long a = b2 + (long)(128 + n) * 256 + k;
        Th[a] = 0;
        Tl[a] = 0;
    }
    for (int part = 0; part < 3; part++) {
        const float* src;
        int nofs, kofs;
        if (y) {
            if (part == 2) break;
            src = part ? (BLW + b1) : (L_old + (long)o * 16384);
            nofs = 0;
            kofs = part ? 128 : 0;
        } else {
            src = (part == 0) ? (Linv1 + b1) : (part == 1) ? (BLi + b1) : (Linv2 + b1);
            nofs = (part == 2) ? 128 : 0;
            kofs = (part == 0) ? 0 : 128;
        }
        for (int bi = 0; bi < 4; bi++)
            for (int bj = 0; bj < 4; bj++) {
                __syncthreads();
                for (int r = ty; r < 32; r += 8)
                    tile[r][tx] = src[(long)(bi * 32 + r) * 128 + bj * 32 + tx];
                __syncthreads();
                for (int r = ty; r < 32; r += 8) {
                    ushort_t hb, lb;
                    splitbf(tile[tx][r], hb, lb);
                    long a = b2 + (long)(nofs + bj * 32 + r) * 256 + kofs + bi * 32 + tx;
                    Th[a] = hb;
                    Tl[a] = lb;
                }
            }
    }
}

// split-bf16 MFMA batched GEMM: C = alpha*(Ah+Al)(Bh+Bl)^T [+ Dm]
// optional fused matvec: CVat += C @ MJv (per-row partials via in-wave reduce + atomicAdd)
#define BSTR 56
template <int TILES3>
__global__ __launch_bounds__(256) void k_bmmx(const ushort_t* __restrict__ Ah,
                                              const ushort_t* __restrict__ Al,
                                              const ushort_t* __restrict__ Bh,
                                              const ushort_t* __restrict__ Bl,
                                              float* __restrict__ Cf,
                                              ushort_t* __restrict__ Chi,
                                              ushort_t* __restrict__ Clo,
                                              const float* __restrict__ Dm,
                                              int kLoMode, float alpha,
                                              const float* __restrict__ MJv,
                                              float* __restrict__ CVat) {
    int pair = blockIdx.x;
    long base = (long)pair * 65536;
    int I0, J0, mir = 0;
    if (TILES3) {
        int qb = blockIdx.y;
        I0 = (qb == 0) ? 0 : 128;
        J0 = (qb == 2) ? 0 : I0;
        mir = (qb == 2);
    } else {
        I0 = (blockIdx.y >> 1) * 128;
        J0 = (blockIdx.y & 1) * 128;
    }
    int k0 = (kLoMode == 1) ? max(I0, J0) : (kLoMode == 2) ? J0 : 0;
    int t = threadIdx.x;
    int w = t >> 6, lane = t & 63;
    int l31 = lane & 31, lhalf = lane >> 5;
    int wy = w >> 1, wx = w & 1;

    __shared__ __align__(16) ushort_t AsH[128][BSTR], AsL[128][BSTR];
    __shared__ __align__(16) ushort_t BsH[128][BSTR], BsL[128][BSTR];

    v16f acc[2][2];
#pragma unroll
    for (int mt = 0; mt < 2; mt++)
#pragma unroll
        for (int nt = 0; nt < 2; nt++)
#pragma unroll
            for (int r = 0; r < 16; r++) acc[mt][nt][r] = 0.f;

    for (int kt = k0; kt < 256; kt += 32) {
        __syncthreads();
#pragma unroll
        for (int u = 0; u < 2; u++) {
            int idx = u * 256 + t;
            int m = idx >> 2, kc = (idx & 3) * 8;
            long arow = base + (long)(I0 + m) * 256 + kt + kc;
            long brow = base + (long)(J0 + m) * 256 + kt + kc;
            *(v8us*)&AsH[m][kc] = *(const v8us*)(Ah + arow);
            *(v8us*)&AsL[m][kc] = *(const v8us*)(Al + arow);
            *(v8us*)&BsH[m][kc] = *(const v8us*)(Bh + brow);
            *(v8us*)&BsL[m][kc] = *(const v8us*)(Bl + brow);
        }
        __syncthreads();
#pragma unroll
        for (int ks = 0; ks < 2; ks++) {
            int ko = ks * 16 + lhalf * 8;
            v8bf ah[2], al[2], bh[2], bl[2];
#pragma unroll
            for (int mt = 0; mt < 2; mt++) {
                int r = wy * 64 + mt * 32 + l31;
                ah[mt] = *(const v8bf*)&AsH[r][ko];
                al[mt] = *(const v8bf*)&AsL[r][ko];
            }
#pragma unroll
            for (int nt = 0; nt < 2; nt++) {
                int r = wx * 64 + nt * 32 + l31;
                bh[nt] = *(const v8bf*)&BsH[r][ko];
                bl[nt] = *(const v8bf*)&BsL[r][ko];
            }
#pragma unroll
            for (int mt = 0; mt < 2; mt++)
#pragma unroll
                for (int nt = 0; nt < 2; nt++) {
                    acc[mt][nt] = __builtin_amdgcn_mfma_f32_32x32x16_bf16(ah[mt], bh[nt], acc[mt][nt], 0, 0, 0);
                    acc[mt][nt] = __builtin_amdgcn_mfma_f32_32x32x16_bf16(ah[mt], bl[nt], acc[mt][nt], 0, 0, 0);
                    acc[mt][nt] = __builtin_amdgcn_mfma_f32_32x32x16_bf16(al[mt], bh[nt], acc[mt][nt], 0, 0, 0);
                }
        }
    }

    float mjc[2] = {0.f, 0.f};
    float cvmir[2] = {0.f, 0.f};
    if (MJv) {
#pragma unroll
        for (int nt = 0; nt < 2; nt++)
            mjc[nt] = MJv[(long)pair * 256 + J0 + wx * 64 + nt * 32 + l31];
    }
#pragma unroll
    for (int mt = 0; mt < 2; mt++) {
#pragma unroll
        for (int r = 0; r < 16; r++) {
            int row = I0 + wy * 64 + mt * 32 + 8 * (r >> 2) + 4 * lhalf + (r & 3);
            float rowsum = 0.f;
            float mjrow = 0.f;
            if (MJv && mir) mjrow = MJv[(long)pair * 256 + row];
#pragma unroll
            for (int nt = 0; nt < 2; nt++) {
                int col = J0 + wx * 64 + nt * 32 + l31;
                long idx = base + (long)row * 256 + col;
                float v = alpha * acc[mt][nt][r];
                if (Dm) v += Dm[idx];
                ushort_t hb, lb;
                splitbf(v, hb, lb);
                if (Cf) Cf[idx] = v;
                if (Chi) { Chi[idx] = hb; Clo[idx] = lb; }
                if (mir) {
                    long idxT = base + (long)col * 256 + row;
                    if (Cf) Cf[idxT] = v;
                    if (Chi) { Chi[idxT] = hb; Clo[idxT] = lb; }
                }
                if (MJv) {
                    rowsum += v * mjc[nt];
                    if (mir) cvmir[nt] += v * mjrow;
                }
            }
            if (MJv) {
#pragma unroll
                for (int m = 1; m < 32; m <<= 1) rowsum += __shfl_xor(rowsum, m, 64);
                if (l31 == 0) atomicAdd(&CVat[(long)pair * 256 + row], rowsum);
            }
        }
    }
    if (MJv && mir) {
#pragma unroll
        for (int nt = 0; nt < 2; nt++)
            atomicAdd(&CVat[(long)pair * 256 + J0 + wx * 64 + nt * 32 + l31], cvmir[nt]);
    }
}

#define KTP 280
// K build: per (bt, pair): compute K tile (fp32 kv), write bf16 K to global, fold mu
__global__ __launch_bounds__(256) void k_kbuild(const float* __restrict__ ZS, const float* __restrict__ ZN,
                                                const float* __restrict__ XS, const float* __restrict__ XN,
                                                const float* __restrict__ SF2, const float* __restrict__ CV,
                                                ushort_t* __restrict__ Kg, float* __restrict__ out) {
    int bt = blockIdx.x;    // 16
    int pair = blockIdx.y;  // 128
    int h = pair >> 5;
    int t = threadIdx.x;
    int w = t >> 6;
    int b = t & 63;

    __shared__ __align__(16) ushort_t KbT[64][KTP];
    __shared__ float mup[4][64];

    float sf2 = SF2[h];
    long bg = (long)h * B_ + bt * 64 + b;
    const float4* xrow = (const float4*)(XS + bg * 16);
    float4 x0 = xrow[0], x1 = xrow[1], x2 = xrow[2], x3 = xrow[3];
    float xn = XN[bg];
    float mupart = 0.f;
    const float* cvp = CV + pair * 256;
    const float* znp = ZN + pair * 256;
#pragma unroll 2
    for (int j8 = 0; j8 < 8; j8++) {
        v8us kb8;
#pragma unroll
        for (int e = 0; e < 8; e++) {
            int j = w * 64 + j8 * 8 + e;
            const float4* zrow = (const float4*)(ZS + ((long)pair * 256 + j) * 16);
            float4 z0 = zrow[0], z1 = zrow[1], z2 = zrow[2], z3 = zrow[3];
            float dot = z0.x * x0.x + z0.y * x0.y + z0.z * x0.z + z0.w * x0.w +
                        z1.x * x1.x + z1.y * x1.y + z1.z * x1.z + z1.w * x1.w +
                        z2.x * x2.x + z2.y * x2.y + z2.z * x2.z + z2.w * x2.w +
                        z3.x * x3.x + z3.y * x3.y + z3.z * x3.z + z3.w * x3.w;
            float d2 = fmaxf(znp[j] + xn - 2.f * dot, 0.f);
            float kv = sf2 * __expf(-0.5f * d2);
            mupart += cvp[j] * kv;
            unsigned int u = __float_as_uint(kv);
            u += 0x7fffu + ((u >> 16) & 1u);
            kb8[e] = (unsigned short)(u >> 16);
        }
        *(v8us*)&KbT[b][w * 64 + j8 * 8] = kb8;
    }
    mup[w][b] = mupart;
    __syncthreads();
    long kbase = ((long)pair * 1024 + bt * 64) * 256;
#pragma unroll
    for (int e = 0; e < 8; e++) {
        int c = e * 256 + t;
        int bb = c >> 5, cj = (c & 31) * 8;
        *(v8us*)(Kg + kbase + (long)bb * 256 + cj) = *(const v8us*)&KbT[bb][cj];
    }
    if (t < 64) {
        float mu = mup[0][t] + mup[1][t] + mup[2][t] + mup[3][t];
        out[(long)pair * 1024 + bt * 64 + t] = mu;
    }
}

// MFMA q kernel, 128-wide b-tiles: 1D grid, pair = idx&127 (XCD L2 locality for G)
#define KT2 264
__global__ __launch_bounds__(256) void k_kb4(const ushort_t* __restrict__ Kg,
                                             const ushort_t* __restrict__ Ghi,
                                             const ushort_t* __restrict__ Glo,
                                             const float* __restrict__ SF2, float* __restrict__ out) {
    int pair = blockIdx.x & 127;
    int bt = blockIdx.x >> 7;  // 0..7
    int h = pair >> 5;
    int t = threadIdx.x;
    int w = t >> 6;
    int lane = t & 63;
    int l31 = lane & 31, lhalf = lane >> 5;

    __shared__ __align__(16) ushort_t KbT[128][KT2];
    __shared__ float qpart[4][128];

    float sf2 = SF2[h];
    long kbase = ((long)pair * 1024 + bt * 128) * 256;
#pragma unroll
    for (int e = 0; e < 16; e++) {
        int c = e * 256 + t;
        int bb = c >> 5, cj = (c & 31) * 8;
        *(v8us*)&KbT[bb][cj] = *(const v8us*)(Kg + kbase + (long)bb * 256 + cj);
    }
    __syncthreads();

    v16f acc[2][4];
#pragma unroll
    for (int mt = 0; mt < 2; mt++)
#pragma unroll
        for (int nt = 0; nt < 4; nt++)
#pragma unroll
            for (int r = 0; r < 16; r++) acc[mt][nt][r] = 0.f;

    const ushort_t* GhiP = Ghi + (long)pair * 65536;
    const ushort_t* GloP = Glo + (long)pair * 65536;
#pragma unroll 2
    for (int k0 = 0; k0 < 256; k0 += 16) {
        v8bf bfr[4];
#pragma unroll
        for (int nt = 0; nt < 4; nt++)
            bfr[nt] = *(const v8bf*)&KbT[nt * 32 + l31][k0 + lhalf * 8];
#pragma unroll
        for (int mt = 0; mt < 2; mt++) {
            int i = w * 64 + mt * 32 + l31;
            v8bf ah = *(const v8bf*)(GhiP + (long)i * 256 + k0 + lhalf * 8);
            v8bf al = *(const v8bf*)(GloP + (long)i * 256 + k0 + lhalf * 8);
#pragma unroll
            for (int nt = 0; nt < 4; nt++) {
                acc[mt][nt] = __builtin_amdgcn_mfma_f32_32x32x16_bf16(ah, bfr[nt], acc[mt][nt], 0, 0, 0);
                acc[mt][nt] = __builtin_amdgcn_mfma_f32_32x32x16_bf16(al, bfr[nt], acc[mt][nt], 0, 0, 0);
            }
        }
    }

    float qp[4] = {0.f, 0.f, 0.f, 0.f};
#pragma unroll
    for (int mt = 0; mt < 2; mt++) {
#pragma unroll
        for (int nt = 0; nt < 4; nt++) {
            int b = nt * 32 + l31;
#pragma unroll
            for (int g = 0; g < 4; g++) {
                int ibase = w * 64 + mt * 32 + 8 * g + 4 * lhalf;
                v4us k4 = *(const v4us*)&KbT[b][ibase];
#pragma unroll
                for (int e = 0; e < 4; e++) {
                    float kv = bf2f(k4[e]);
                    qp[nt] += kv * acc[mt][nt][4 * g + e];
                }
            }
        }
    }
#pragma unroll
    for (int nt = 0; nt < 4; nt++) {
        qp[nt] += __shfl_down(qp[nt], 32, 64);
        if (lhalf == 0) qpart[w][nt * 32 + l31] = qp[nt];
    }
    __syncthreads();

    if (t < 128) {
        float q = qpart[0][t] + qpart[1][t] + qpart[2][t] + qpart[3][t];
        out[(long)H_ * O_ * B_ + (long)pair * 1024 + bt * 128 + t] = sf2 - q;
    }
}

// ---------------------------------------------------------------------------
extern "C" void kernel_launch(void* const* d_in, const int* in_sizes, int n_in,
                              void* d_out, int out_size, void* d_ws, size_t ws_size,
                              hipStream_t stream) {
    const float* x = (const float*)d_in[0];
    const float* z = (const float*)d_in[1];
    const float* u_mean = (const float*)d_in[2];
    const float* u_tril_vec = (const float*)d_in[3];
    const float* m_old = (const float*)d_in[4];
    const float* L_old = (const float*)d_in[5];
    const float* z_old = (const float*)d_in[6];
    const float* theta = (const float*)d_in[7];

    const long BIGSZ = (long)HO * M2 * M2;  // 8388608
    const long MSZ = (long)HO * M_ * M_;    // 2097152
    const long SH1 = (long)O_ * M_ * M_;
    const long SO1 = (long)M_ * M_;
    const long SO2 = (long)M2 * M2;

    float* ws = (float*)d_ws;
    long off = 0;
    float* BIG0 = ws + off; off += BIGSZ;  // KUU2 -> T1/BLi -> AINV fp32
    float* BIG1 = ws + off; off += BIGSZ;  // LINVT h/l -> Y h/l -> Kg (part 1)
    float* BIG2 = ws + off; off += BIGSZ;  // Linv1|A1|Linv2|BLW -> AINV h/l -> Kg (part 2)
    float* BIG3 = ws + off; off += BIGSZ;  // WcT h/l -> G h/l
    float* ZS = ws + off; off += (long)HO * M2 * D_;
    float* XS = ws + off; off += (long)H_ * B_ * D_;
    float* ZN = ws + off; off += (long)HO * M2;
    float* XN = ws + off; off += (long)H_ * B_;
    float* MJ = ws + off; off += (long)HO * M2;
    float* CV = ws + off; off += (long)HO * M2;
    float* SF2v = ws + off; off += H_;

    float* KUU2 = BIG0;
    float* AINV = BIG0;
    float* Linv1 = BIG2;
    float* A1 = BIG2 + MSZ;
    float* A3 = BIG2 + 2 * MSZ;
    float* Linv2 = BIG2 + 2 * MSZ;
    float* BLW = BIG2 + 3 * MSZ;
    float* T1 = BIG0;                // over KUU2 TL (dead after choltri BR)
    float* BLi = BIG0 + MSZ;         // over KUU2 (dead) — NOT in BIG3 (k_split2 aliasing)
    ushort_t* LINVTh = (ushort_t*)BIG1;
    ushort_t* LINVTl = LINVTh + BIGSZ;
    ushort_t* AINVh = (ushort_t*)BIG2;
    ushort_t* AINVl = AINVh + BIGSZ;
    ushort_t* WcTh = (ushort_t*)BIG3;
    ushort_t* WcTl = WcTh + BIGSZ;
    ushort_t* Yh = (ushort_t*)BIG1;
    ushort_t* Yl = Yh + BIGSZ;
    ushort_t* Ghi = (ushort_t*)BIG3;
    ushort_t* Glo = Ghi + BIGSZ;
    ushort_t* Kg = (ushort_t*)BIG1;  // 64 MB spanning BIG1+BIG2 (both dead by then)
    const long BRoff = 128L * M2 + 128;

    // 1. preprocessing + kuu2 (fused)
    k_prekuu2<<<145, 256, 0, stream>>>(theta, x, z, z_old, SF2v, XS, XN, ZS, ZN, KUU2);
    // 2. chol TL + trinv -> Linv1 (register/wave-sync core)
    k_choltri<<<HO, 256, 0, stream>>>(KUU2, SO2, M2, Linv1);
    // 3. A1 = Linv1@kuf ; A3 = Linv1@L_old (merged)
    k_a1a3<<<dim3(HO, 2), 256, 0, stream>>>(Linv1, KUU2, L_old, A1, A3);
    // 4. m_joint
    k_stage1vec<<<HO, 128, 0, stream>>>(Linv1, A1, m_old, u_mean, MJ);
    // 5. BLW = A1^T A3 ; KUU2_BR -= A1^T A1 (merged)
    k_blwschur<<<dim3(HO, 2), 256, 0, stream>>>(A1, A3, BLW, KUU2);
    // 6. chol BR + trinv -> Linv2 (over A3 slot — dead)
    k_choltri<<<HO, 256, 0, stream>>>(KUU2 + BRoff, SO2, M2, Linv2);
    // 7. T1 = A1^T @ Linv1 (into BIG0 — KUU2 dead)
    k_bmm<1, 0><<<HO, 256, 0, stream>>>(A1, SH1, SO1, M_, Linv1, SH1, SO1, M_,
                                        T1, SH1, SO1, M_, M_, 1.f, 0);
    // 8. BLi = -Linv2 @ T1 (into BIG0+MSZ)
    k_bmm<0, 0><<<HO, 256, 0, stream>>>(Linv2, SH1, SO1, M_, T1, SH1, SO1, M_,
                                        BLi, SH1, SO1, M_, M_, -1.f, 0);
    // 9. LINVT + WcT planes (merged; BLi in BIG0, WcT in BIG3 — disjoint)
    k_split2<<<dim3(HO, 2), 256, 0, stream>>>(Linv1, BLi, Linv2, L_old, BLW, u_tril_vec,
                                              LINVTh, LINVTl, WcTh, WcTl);
    // 10. zero CV for fused matvec
    hipMemsetAsync(CV, 0, (long)HO * M2 * sizeof(float), stream);
    // 11. AINV = LINVT (.) LINVT -> fp32 (BIG0; T1/BLi dead) + planes (BIG2) + CV fused
    k_bmmx<1><<<dim3(HO, 3), 256, 0, stream>>>(LINVTh, LINVTl, LINVTh, LINVTl,
                                               AINV, AINVh, AINVl, nullptr, 1, 1.f, MJ, CV);
    // 12. Y = AINV @ Wc -> Y planes (BIG1; LINVT dead)
    k_bmmx<0><<<dim3(HO, 4), 256, 0, stream>>>(AINVh, AINVl, WcTh, WcTl,
                                               nullptr, Yh, Yl, nullptr, 2, 1.f, nullptr, nullptr);
    // 13. G = AINV - Y Y^T -> G planes (BIG3; WcT dead)
    k_bmmx<1><<<dim3(HO, 3), 256, 0, stream>>>(Yh, Yl, Yh, Yl,
                                               nullptr, Ghi, Glo, AINV, 0, -1.f, nullptr, nullptr);
    // 14. K build + mu (Kg over BIG1+BIG2 — Y and AINV planes dead)
    k_kbuild<<<dim3(16, HO), 256, 0, stream>>>(ZS, ZN, XS, XN, SF2v, CV, Kg, (float*)d_out);
    // 15. MFMA q/var, 128-wide b-tiles
    k_kb4<<<1024, 256, 0, stream>>>(Kg, Ghi, Glo, SF2v, (float*)d_out);
}

// Round 12
// 745.955 us; speedup vs baseline: 1.2698x; 1.2698x over previous
//
#include <hip/hip_runtime.h>

#define H_ 4
#define O_ 32
#define HO 128
#define M_ 128
#define M2 256
#define D_ 16
#define B_ 1024
#define JIT 1e-4f

typedef unsigned short ushort_t;
typedef __bf16 v8bf __attribute__((ext_vector_type(8)));
typedef float v16f __attribute__((ext_vector_type(16)));
typedef unsigned short v8us __attribute__((ext_vector_type(8)));
typedef unsigned short v4us __attribute__((ext_vector_type(4)));

__device__ inline void splitbf(float v, ushort_t& hb, ushort_t& lb) {
    unsigned int u = __float_as_uint(v);
    hb = (ushort_t)(u >> 16);
    float hf = __uint_as_float((unsigned int)hb << 16);
    float r = v - hf;
    lb = (ushort_t)(__float_as_uint(r) >> 16);
}
__device__ inline float bf2f(ushort_t u) { return __uint_as_float((unsigned int)u << 16); }

// ---------------------------------------------------------------------------
// merged preprocessing + kuu2
__global__ __launch_bounds__(256) void k_prekuu2(const float* __restrict__ theta,
                                                 const float* __restrict__ x,
                                                 const float* __restrict__ z,
                                                 const float* __restrict__ z_old,
                                                 float* __restrict__ SF2,
                                                 float* __restrict__ XS, float* __restrict__ XN,
                                                 float* __restrict__ ZS, float* __restrict__ ZN,
                                                 float* __restrict__ K2) {
    int bb = blockIdx.x, t = threadIdx.x;
    __shared__ float zs[M2][D_];
    __shared__ float zn[M2];
    __shared__ float ls[D_];
    if (bb == 144) {
        if (t < H_) SF2[t] = __expf(theta[t * (D_ + 1)]);
        return;
    }
    if (bb >= 128) {
        int j = (bb - 128) * 256 + t;
        int h = j >> 10, b = j & 1023;
        if (t < D_) ls[t] = __expf(-theta[h * (D_ + 1) + 1 + t]);
        __syncthreads();
        float s = 0.f;
#pragma unroll
        for (int d = 0; d < D_; d++) {
            float v = x[b * D_ + d] * ls[d];
            XS[(long)j * D_ + d] = v;
            s += v * v;
        }
        XN[j] = s;
        return;
    }
    int pair = bb, h = pair >> 5, o = pair & 31, i = t;
    if (t < D_) ls[t] = __expf(-theta[h * (D_ + 1) + 1 + t]);
    __syncthreads();
    const float* src = (i < M_) ? (z_old + ((long)o * M_ + i) * D_)
                                : (z + ((long)o * M_ + (i - M_)) * D_);
    float s = 0.f;
#pragma unroll
    for (int d = 0; d < D_; d++) {
        float v = src[d] * ls[d];
        zs[i][d] = v;
        ZS[((long)pair * M2 + i) * D_ + d] = v;
        s += v * v;
    }
    zn[i] = s;
    ZN[pair * M2 + i] = s;
    __syncthreads();
    float sf2 = __expf(theta[h * (D_ + 1)]);
    float my[D_];
#pragma unroll
    for (int d = 0; d < D_; d++) my[d] = zs[i][d];
    float myn = zn[i];
    for (int q = 0; q < M2; q++) {
        float dot = 0.f;
#pragma unroll
        for (int d = 0; d < D_; d++) dot += zs[q][d] * my[d];
        float d2 = fmaxf(zn[q] + myn - 2.f * dot, 0.f);
        float v = sf2 * __expf(-0.5f * d2);
        if (q == i) v += JIT;
        K2[(long)pair * M2 * M2 + (long)q * M2 + i] = v;
    }
}

// fused: blocked (BK=32) in-LDS Cholesky of a 128x128 block, then triangular
// inverse of the resulting L — all in LDS, writes full Linv (zero upper).
// (R10 version — loop-based; register/unrolled variant regressed 2x: icache-bound)
__global__ __launch_bounds__(256) void k_choltri(const float* __restrict__ src, long sps, int ldsrc,
                                                 float* __restrict__ Li) {
    int pair = blockIdx.x, t = threadIdx.x;
    __shared__ float Ap[M_ * (M_ + 1) / 2];
    __shared__ float rsq[32];
    __shared__ float Ld[2][64][66], Wd[2][64][66], LB[64][66], Tt[64][66];
    const float* S = src + (long)pair * sps;
    for (int e = t; e < M_ * (M_ + 1) / 2; e += 256) {
        int i = (int)((sqrtf(8.f * e + 1.f) - 1.f) * 0.5f);
        while ((i + 1) * (i + 2) / 2 <= e) i++;
        while (i * (i + 1) / 2 > e) i--;
        int j = e - i * (i + 1) / 2;
        Ap[e] = S[(long)i * ldsrc + j];
    }
    int pi[3], pj[3];
#pragma unroll
    for (int u = 0; u < 3; u++) {
        int p = t + u * 256;
        if (p < 528) {
            int i = (int)((sqrtf(8.f * p + 1.f) - 1.f) * 0.5f);
            while ((i + 1) * (i + 2) / 2 <= p) i++;
            while (i * (i + 1) / 2 > p) i--;
            pi[u] = i;
            pj[u] = p - i * (i + 1) / 2;
        } else {
            pi[u] = -1;
            pj[u] = 0;
        }
    }
    __syncthreads();

    for (int kb = 0; kb < 4; kb++) {
        int c0 = kb * 32;
        for (int k = 0; k < 32; k++) {
            int kc = c0 + k;
            float rd = 1.f / Ap[kc * (kc + 1) / 2 + kc];
#pragma unroll
            for (int u = 0; u < 3; u++) {
                int i = pi[u], j = pj[u];
                if (i > k && j > k) {
                    int gi = c0 + i, gj = c0 + j;
                    Ap[gi * (gi + 1) / 2 + gj] -=
                        Ap[gi * (gi + 1) / 2 + kc] * Ap[gj * (gj + 1) / 2 + kc] * rd;
                }
            }
            __syncthreads();
        }
        if (t < 32) {
            int g = c0 + t;
            rsq[t] = rsqrtf(Ap[g * (g + 1) / 2 + g]);
        }
        __syncthreads();
#pragma unroll
        for (int u = 0; u < 3; u++) {
            int i = pi[u], j = pj[u];
            if (i >= 0) {
                int gi = c0 + i, gj = c0 + j;
                Ap[gi * (gi + 1) / 2 + gj] *= rsq[j];
            }
        }
        __syncthreads();

        int R = M_ - c0 - 32;
        if (R > 0) {
            if (t < R) {
                int gi = c0 + 32 + t;
                int base = gi * (gi + 1) / 2 + c0;
                float xr[32];
#pragma unroll
                for (int j = 0; j < 32; j++) xr[j] = Ap[base + j];
#pragma unroll
                for (int q = 0; q < 32; q++) {
                    float xq = xr[q] * rsq[q];
                    xr[q] = xq;
#pragma unroll
                    for (int j = q + 1; j < 32; j++)
                        xr[j] -= xq * Ap[(c0 + j) * (c0 + j + 1) / 2 + c0 + q];
                }
#pragma unroll
                for (int j = 0; j < 32; j++) Ap[base + j] = xr[j];
            }
            __syncthreads();
            int nb = R >> 2;
            int ntile = nb * (nb + 1) / 2;
            for (int tp = t; tp < ntile; tp += 256) {
                int bi = (int)((sqrtf(8.f * tp + 1.f) - 1.f) * 0.5f);
                while ((bi + 1) * (bi + 2) / 2 <= tp) bi++;
                while (bi * (bi + 1) / 2 > tp) bi--;
                int bj = tp - bi * (bi + 1) / 2;
                int i0 = c0 + 32 + bi * 4, j0 = c0 + 32 + bj * 4;
                float acc[4][4] = {};
                for (int k = 0; k < 32; k++) {
                    float a[4], b[4];
#pragma unroll
                    for (int q = 0; q < 4; q++) a[q] = Ap[(i0 + q) * (i0 + q + 1) / 2 + c0 + k];
#pragma unroll
                    for (int r = 0; r < 4; r++) b[r] = Ap[(j0 + r) * (j0 + r + 1) / 2 + c0 + k];
#pragma unroll
                    for (int q = 0; q < 4; q++)
#pragma unroll
                        for (int r = 0; r < 4; r++) acc[q][r] += a[q] * b[r];
                }
#pragma unroll
                for (int q = 0; q < 4; q++)
#pragma unroll
                    for (int r = 0; r < 4; r++) {
                        int gi = i0 + q, gj = j0 + r;
                        if (gj <= gi) Ap[gi * (gi + 1) / 2 + gj] -= acc[q][r];
                    }
            }
            __syncthreads();
        }
    }

    // ---- trinv from packed L in Ap ----
    for (int e = t; e < 8192; e += 256) {
        int g = e >> 12, i = (e >> 6) & 63, j = e & 63;
        int gi = g * 64 + i, gj = g * 64 + j;
        Ld[g][i][j] = (j <= i) ? Ap[gi * (gi + 1) / 2 + gj] : 0.f;
    }
    for (int e = t; e < 4096; e += 256) {
        int i = e >> 6, j = e & 63;
        int gi = 64 + i;
        LB[i][j] = Ap[gi * (gi + 1) / 2 + j];
    }
    __syncthreads();
    if (t < 128) {
        int g = t >> 6, c = t & 63;
        for (int i = 0; i < 64; i++) {
            float acc = (i == c) ? 1.f : 0.f;
            for (int j = 0; j < i; j++) acc -= Ld[g][i][j] * Wd[g][j][c];
            Wd[g][i][c] = acc / Ld[g][i][i];
        }
    }
    __syncthreads();
    long b1 = (long)pair * 16384;
    int ti = t >> 4, tj = t & 15;
    float acc[4][4] = {};
    for (int kk = 0; kk < 64; kk++) {
        float a[4], b[4];
#pragma unroll
        for (int q = 0; q < 4; q++) a[q] = LB[ti * 4 + q][kk];
#pragma unroll
        for (int r = 0; r < 4; r++) b[r] = Wd[0][kk][tj * 4 + r];
#pragma unroll
        for (int q = 0; q < 4; q++)
#pragma unroll
            for (int r = 0; r < 4; r++) acc[q][r] += a[q] * b[r];
    }
#pragma unroll
    for (int q = 0; q < 4; q++)
#pragma unroll
        for (int r = 0; r < 4; r++) Tt[ti * 4 + q][tj * 4 + r] = acc[q][r];
    __syncthreads();
    float xo[4][4] = {};
    for (int kk = 0; kk < 64; kk++) {
        float a[4], b[4];
#pragma unroll
        for (int q = 0; q < 4; q++) a[q] = Wd[1][ti * 4 + q][kk];
#pragma unroll
        for (int r = 0; r < 4; r++) b[r] = Tt[kk][tj * 4 + r];
#pragma unroll
        for (int q = 0; q < 4; q++)
#pragma unroll
            for (int r = 0; r < 4; r++) xo[q][r] -= a[q] * b[r];
    }
#pragma unroll
    for (int q = 0; q < 4; q++)
#pragma unroll
        for (int r = 0; r < 4; r++)
            Li[b1 + (long)(64 + ti * 4 + q) * 128 + tj * 4 + r] = xo[q][r];
    for (int e = t; e < 4096; e += 256) {
        int i = e >> 6, j = e & 63;
        Li[b1 + (long)i * 128 + j] = Wd[0][i][j];
        Li[b1 + (long)(64 + i) * 128 + 64 + j] = Wd[1][i][j];
        Li[b1 + (long)i * 128 + 64 + j] = 0.f;
    }
}

// merged A1/A3: y=0: A1 = Linv1 @ kuf(KUU2 TR); y=1: A3 = Linv1 @ L_old
__global__ __launch_bounds__(256) void k_a1a3(const float* __restrict__ Linv1,
                                              const float* __restrict__ KUU2,
                                              const float* __restrict__ L_old,
                                              float* __restrict__ A1, float* __restrict__ A3) {
    int pair = blockIdx.x, y = blockIdx.y, o = pair & 31;
    const float* Ap = Linv1 + (long)pair * 16384;
    const float* Bp = y ? (L_old + (long)o * 16384) : (KUU2 + (long)pair * 65536 + 128);
    int ldb = y ? 128 : 256;
    float* Cp = (y ? A3 : A1) + (long)pair * 16384;
    int t = threadIdx.x, tx = t & 15, ty = t >> 4;
    __shared__ float As[16][132], Bs[16][132];
    float acc[8][8] = {};
    for (int kt = 0; kt < M_; kt += 16) {
#pragma unroll
        for (int q = 0; q < 8; q++) {
            int e = q * 256 + t;
            int m = e >> 4, kk = e & 15;
            As[kk][m] = Ap[(long)m * 128 + kt + kk];
            int kk2 = e >> 7, n = e & 127;
            Bs[kk2][n] = Bp[(long)(kt + kk2) * ldb + n];
        }
        __syncthreads();
#pragma unroll
        for (int kk = 0; kk < 16; kk++) {
            float a[8], b[8];
#pragma unroll
            for (int q = 0; q < 8; q++) { a[q] = As[kk][ty + 16 * q]; b[q] = Bs[kk][tx + 16 * q]; }
#pragma unroll
            for (int q = 0; q < 8; q++)
#pragma unroll
                for (int r = 0; r < 8; r++) acc[q][r] += a[q] * b[r];
        }
        __syncthreads();
    }
#pragma unroll
    for (int q = 0; q < 8; q++)
#pragma unroll
        for (int r = 0; r < 8; r++)
            Cp[(long)(ty + 16 * q) * 128 + tx + 16 * r] = acc[q][r];
}

// merged BLW/Schur/stage1vec: y=0: BLW = A1^T A3; y=1: KUU2_BR -= A1^T A1;
// y=2: m_joint (a2 = Linv1*m_old; m_new = A1^T a2 + u_mean)
__global__ __launch_bounds__(256) void k_blwschur(const float* __restrict__ A1,
                                                  const float* __restrict__ A3,
                                                  float* __restrict__ BLW,
                                                  float* __restrict__ KUU2,
                                                  const float* __restrict__ Linv1,
                                                  const float* __restrict__ m_old,
                                                  const float* __restrict__ u_mean,
                                                  float* __restrict__ MJ) {
    int pair = blockIdx.x, y = blockIdx.y, o = pair & 31;
    int t = threadIdx.x;
    if (y == 2) {
        __shared__ float mo[128], a2[128];
        if (t < 128) mo[t] = m_old[o * 128 + t];
        __syncthreads();
        if (t < 128) {
            const float* Lr = Linv1 + (long)pair * 16384 + (long)t * 128;
            float acc = 0.f;
            for (int j = 0; j <= t; j++) acc += Lr[j] * mo[j];
            a2[t] = acc;
        }
        __syncthreads();
        if (t < 128) {
            float m = 0.f;
            for (int i = 0; i < 128; i++) m += A1[(long)pair * 16384 + (long)i * 128 + t] * a2[i];
            MJ[pair * 256 + t] = mo[t];
            MJ[pair * 256 + 128 + t] = m + u_mean[o * 128 + t];
        }
        return;
    }
    const float* Ap = A1 + (long)pair * 16384;
    const float* Bp = (y ? A1 : A3) + (long)pair * 16384;
    float* Cp;
    int ldc;
    if (y) { Cp = KUU2 + (long)pair * 65536 + 128L * 256 + 128; ldc = 256; }
    else   { Cp = BLW + (long)pair * 16384; ldc = 128; }
    int tx = t & 15, ty = t >> 4;
    __shared__ float As[16][132], Bs[16][132];
    float acc[8][8] = {};
    for (int kt = 0; kt < M_; kt += 16) {
#pragma unroll
        for (int q = 0; q < 8; q++) {
            int e = q * 256 + t;
            int kk = e >> 7, m = e & 127;
            As[kk][m] = Ap[(long)(kt + kk) * 128 + m];
            Bs[kk][m] = Bp[(long)(kt + kk) * 128 + m];
        }
        __syncthreads();
#pragma unroll
        for (int kk = 0; kk < 16; kk++) {
            float a[8], b[8];
#pragma unroll
            for (int q = 0; q < 8; q++) { a[q] = As[kk][ty + 16 * q]; b[q] = Bs[kk][tx + 16 * q]; }
#pragma unroll
            for (int q = 0; q < 8; q++)
#pragma unroll
                for (int r = 0; r < 8; r++) acc[q][r] += a[q] * b[r];
        }
        __syncthreads();
    }
#pragma unroll
    for (int q = 0; q < 8; q++)
#pragma unroll
        for (int r = 0; r < 8; r++) {
            long idx = (long)(ty + 16 * q) * ldc + tx + 16 * r;
            if (y) Cp[idx] -= acc[q][r];
            else Cp[idx] = acc[q][r];
        }
}

// fused T1 (LDS-only) + BLi: T1 = A1^T @ Linv1; BLi = -Linv2 @ T1
__global__ __launch_bounds__(256) void k_blicalc(const float* __restrict__ A1,
                                                 const float* __restrict__ Linv1,
                                                 const float* __restrict__ Linv2,
                                                 float* __restrict__ BLi) {
    int pair = blockIdx.x, t = threadIdx.x, tx = t & 15, ty = t >> 4;
    long b1 = (long)pair * 16384;
    __shared__ float T1s[128][128];  // 64 KB
    __shared__ float As[16][132], Bs[16][132];
    const float* Ap = A1 + b1;
    const float* Bp = Linv1 + b1;
    float acc[8][8] = {};
    for (int kt = 0; kt < M_; kt += 16) {
#pragma unroll
        for (int q = 0; q < 8; q++) {
            int e = q * 256 + t;
            int kk = e >> 7, m = e & 127;
            As[kk][m] = Ap[(long)(kt + kk) * 128 + m];  // A1^T
            Bs[kk][m] = Bp[(long)(kt + kk) * 128 + m];
        }
        __syncthreads();
#pragma unroll
        for (int kk = 0; kk < 16; kk++) {
            float a[8], b[8];
#pragma unroll
            for (int q = 0; q < 8; q++) { a[q] = As[kk][ty + 16 * q]; b[q] = Bs[kk][tx + 16 * q]; }
#pragma unroll
            for (int q = 0; q < 8; q++)
#pragma unroll
                for (int r = 0; r < 8; r++) acc[q][r] += a[q] * b[r];
        }
        __syncthreads();
    }
#pragma unroll
    for (int q = 0; q < 8; q++)
#pragma unroll
        for (int r = 0; r < 8; r++) T1s[ty + 16 * q][tx + 16 * r] = acc[q][r];
    __syncthreads();
    // phase 2: BLi = -Linv2 @ T1s
    const float* Cp2 = Linv2 + b1;
    float acc2[8][8] = {};
    for (int kt = 0; kt < M_; kt += 16) {
#pragma unroll
        for (int q = 0; q < 8; q++) {
            int e = q * 256 + t;
            int m = e >> 4, kk = e & 15;
            As[kk][m] = Cp2[(long)m * 128 + kt + kk];
        }
        __syncthreads();
#pragma unroll
        for (int kk = 0; kk < 16; kk++) {
            float a[8], b[8];
#pragma unroll
            for (int q = 0; q < 8; q++) { a[q] = As[kk][ty + 16 * q]; b[q] = T1s[kt + kk][tx + 16 * q]; }
#pragma unroll
            for (int q = 0; q < 8; q++)
#pragma unroll
                for (int r = 0; r < 8; r++) acc2[q][r] += a[q] * b[r];
        }
        __syncthreads();
    }
#pragma unroll
    for (int q = 0; q < 8; q++)
#pragma unroll
        for (int r = 0; r < 8; r++)
            BLi[b1 + (long)(ty + 16 * q) * 128 + tx + 16 * r] = -acc2[q][r];
}

// merged split-planes kernel: y=0 -> LINVT from (Linv1,BLi,Linv2); y=1 -> WcT from (L_old,BLW,u_tril)
__global__ __launch_bounds__(256) void k_split2(const float* __restrict__ Linv1,
                                                const float* __restrict__ BLi,
                                                const float* __restrict__ Linv2,
                                                const float* __restrict__ L_old,
                                                const float* __restrict__ BLW,
                                                const float* __restrict__ vec,
                                                ushort_t* __restrict__ LTh, ushort_t* __restrict__ LTl,
                                                ushort_t* __restrict__ WTh, ushort_t* __restrict__ WTl) {
    int pair = blockIdx.x, y = blockIdx.y, o = pair & 31, t = threadIdx.x;
    long b2 = (long)pair * 65536, b1 = (long)pair * 16384;
    int tx = t & 31, ty = t >> 5;
    __shared__ float vs[M_ * (M_ + 1) / 2];
    __shared__ float tile[32][33];
    ushort_t* Th = y ? WTh : LTh;
    ushort_t* Tl = y ? WTl : LTl;
    if (y) {
        for (int e = t; e < M_ * (M_ + 1) / 2; e += 256) vs[e] = vec[(long)o * (M_ * (M_ + 1) / 2) + e];
        __syncthreads();
        for (int e = t; e < 16384; e += 256) {
            int n = e >> 7, k = e & 127;
            float v = (k >= n) ? vs[k * (k + 1) / 2 + n] : 0.f;
            ushort_t hb, lb;
            splitbf(v, hb, lb);
            long a = b2 + (long)(128 + n) * 256 + 128 + k;
            Th[a] = hb;
            Tl[a] = lb;
        }
    }
    for (int e = t; e < 16384; e += 256) {
        int n = e >> 7, k = e & 127;
        long a = b2 + (long)(128 + n) * 256 + k;
        Th[a] = 0;
        Tl[a] = 0;
    }
    for (int part = 0; part < 3; part++) {
        const float* src;
        int nofs, kofs;
        if (y) {
            if (part == 2) break;
            src = part ? (BLW + b1) : (L_old + (long)o * 16384);
            nofs = 0;
            kofs = part ? 128 : 0;
        } else {
            src = (part == 0) ? (Linv1 + b1) : (part == 1) ? (BLi + b1) : (Linv2 + b1);
            nofs = (part == 2) ? 128 : 0;
            kofs = (part == 0) ? 0 : 128;
        }
        for (int bi = 0; bi < 4; bi++)
            for (int bj = 0; bj < 4; bj++) {
                __syncthreads();
                for (int r = ty; r < 32; r += 8)
                    tile[r][tx] = src[(long)(bi * 32 + r) * 128 + bj * 32 + tx];
                __syncthreads();
                for (int r = ty; r < 32; r += 8) {
                    ushort_t hb, lb;
                    splitbf(tile[tx][r], hb, lb);
                    long a = b2 + (long)(nofs + bj * 32 + r) * 256 + kofs + bi * 32 + tx;
                    Th[a] = hb;
                    Tl[a] = lb;
                }
            }
    }
}

// split-bf16 MFMA batched GEMM: C = alpha*(Ah+Al)(Bh+Bl)^T [+ Dm]
// optional fused matvec: CVat += C @ MJv
#define BSTR 56
template <int TILES3>
__global__ __launch_bounds__(256) void k_bmmx(const ushort_t* __restrict__ Ah,
                                              const ushort_t* __restrict__ Al,
                                              const ushort_t* __restrict__ Bh,
                                              const ushort_t* __restrict__ Bl,
                                              float* __restrict__ Cf,
                                              ushort_t* __restrict__ Chi,
                                              ushort_t* __restrict__ Clo,
                                              const float* __restrict__ Dm,
                                              int kLoMode, float alpha,
                                              const float* __restrict__ MJv,
                                              float* __restrict__ CVat) {
    int pair = blockIdx.x;
    long base = (long)pair * 65536;
    int I0, J0, mir = 0;
    if (TILES3) {
        int qb = blockIdx.y;
        I0 = (qb == 0) ? 0 : 128;
        J0 = (qb == 2) ? 0 : I0;
        mir = (qb == 2);
    } else {
        I0 = (blockIdx.y >> 1) * 128;
        J0 = (blockIdx.y & 1) * 128;
    }
    int k0 = (kLoMode == 1) ? max(I0, J0) : (kLoMode == 2) ? J0 : 0;
    int t = threadIdx.x;
    int w = t >> 6, lane = t & 63;
    int l31 = lane & 31, lhalf = lane >> 5;
    int wy = w >> 1, wx = w & 1;

    __shared__ __align__(16) ushort_t AsH[128][BSTR], AsL[128][BSTR];
    __shared__ __align__(16) ushort_t BsH[128][BSTR], BsL[128][BSTR];

    v16f acc[2][2];
#pragma unroll
    for (int mt = 0; mt < 2; mt++)
#pragma unroll
        for (int nt = 0; nt < 2; nt++)
#pragma unroll
            for (int r = 0; r < 16; r++) acc[mt][nt][r] = 0.f;

    for (int kt = k0; kt < 256; kt += 32) {
        __syncthreads();
#pragma unroll
        for (int u = 0; u < 2; u++) {
            int idx = u * 256 + t;
            int m = idx >> 2, kc = (idx & 3) * 8;
            long arow = base + (long)(I0 + m) * 256 + kt + kc;
            long brow = base + (long)(J0 + m) * 256 + kt + kc;
            *(v8us*)&AsH[m][kc] = *(const v8us*)(Ah + arow);
            *(v8us*)&AsL[m][kc] = *(const v8us*)(Al + arow);
            *(v8us*)&BsH[m][kc] = *(const v8us*)(Bh + brow);
            *(v8us*)&BsL[m][kc] = *(const v8us*)(Bl + brow);
        }
        __syncthreads();
#pragma unroll
        for (int ks = 0; ks < 2; ks++) {
            int ko = ks * 16 + lhalf * 8;
            v8bf ah[2], al[2], bh[2], bl[2];
#pragma unroll
            for (int mt = 0; mt < 2; mt++) {
                int r = wy * 64 + mt * 32 + l31;
                ah[mt] = *(const v8bf*)&AsH[r][ko];
                al[mt] = *(const v8bf*)&AsL[r][ko];
            }
#pragma unroll
            for (int nt = 0; nt < 2; nt++) {
                int r = wx * 64 + nt * 32 + l31;
                bh[nt] = *(const v8bf*)&BsH[r][ko];
                bl[nt] = *(const v8bf*)&BsL[r][ko];
            }
#pragma unroll
            for (int mt = 0; mt < 2; mt++)
#pragma unroll
                for (int nt = 0; nt < 2; nt++) {
                    acc[mt][nt] = __builtin_amdgcn_mfma_f32_32x32x16_bf16(ah[mt], bh[nt], acc[mt][nt], 0, 0, 0);
                    acc[mt][nt] = __builtin_amdgcn_mfma_f32_32x32x16_bf16(ah[mt], bl[nt], acc[mt][nt], 0, 0, 0);
                    acc[mt][nt] = __builtin_amdgcn_mfma_f32_32x32x16_bf16(al[mt], bh[nt], acc[mt][nt], 0, 0, 0);
                }
        }
    }

    float mjc[2] = {0.f, 0.f};
    float cvmir[2] = {0.f, 0.f};
    if (MJv) {
#pragma unroll
        for (int nt = 0; nt < 2; nt++)
            mjc[nt] = MJv[(long)pair * 256 + J0 + wx * 64 + nt * 32 + l31];
    }
#pragma unroll
    for (int mt = 0; mt < 2; mt++) {
#pragma unroll
        for (int r = 0; r < 16; r++) {
            int row = I0 + wy * 64 + mt * 32 + 8 * (r >> 2) + 4 * lhalf + (r & 3);
            float rowsum = 0.f;
            float mjrow = 0.f;
            if (MJv && mir) mjrow = MJv[(long)pair * 256 + row];
#pragma unroll
            for (int nt = 0; nt < 2; nt++) {
                int col = J0 + wx * 64 + nt * 32 + l31;
                long idx = base + (long)row * 256 + col;
                float v = alpha * acc[mt][nt][r];
                if (Dm) v += Dm[idx];
                ushort_t hb, lb;
                splitbf(v, hb, lb);
                if (Cf) Cf[idx] = v;
                if (Chi) { Chi[idx] = hb; Clo[idx] = lb; }
                if (mir) {
                    long idxT = base + (long)col * 256 + row;
                    if (Cf) Cf[idxT] = v;
                    if (Chi) { Chi[idxT] = hb; Clo[idxT] = lb; }
                }
                if (MJv) {
                    rowsum += v * mjc[nt];
                    if (mir) cvmir[nt] += v * mjrow;
                }
            }
            if (MJv) {
#pragma unroll
                for (int m = 1; m < 32; m <<= 1) rowsum += __shfl_xor(rowsum, m, 64);
                if (l31 == 0) atomicAdd(&CVat[(long)pair * 256 + row], rowsum);
            }
        }
    }
    if (MJv && mir) {
#pragma unroll
        for (int nt = 0; nt < 2; nt++)
            atomicAdd(&CVat[(long)pair * 256 + J0 + wx * 64 + nt * 32 + l31], cvmir[nt]);
    }
}

#define KTP 280
// K build: per (bt, pair): compute K tile (fp32 kv), write bf16 K to global, fold mu
__global__ __launch_bounds__(256) void k_kbuild(const float* __restrict__ ZS, const float* __restrict__ ZN,
                                                const float* __restrict__ XS, const float* __restrict__ XN,
                                                const float* __restrict__ SF2, const float* __restrict__ CV,
                                                ushort_t* __restrict__ Kg, float* __restrict__ out) {
    int bt = blockIdx.x;    // 16
    int pair = blockIdx.y;  // 128
    int h = pair >> 5;
    int t = threadIdx.x;
    int w = t >> 6;
    int b = t & 63;

    __shared__ __align__(16) ushort_t KbT[64][KTP];
    __shared__ float mup[4][64];

    float sf2 = SF2[h];
    long bg = (long)h * B_ + bt * 64 + b;
    const float4* xrow = (const float4*)(XS + bg * 16);
    float4 x0 = xrow[0], x1 = xrow[1], x2 = xrow[2], x3 = xrow[3];
    float xn = XN[bg];
    float mupart = 0.f;
    const float* cvp = CV + pair * 256;
    const float* znp = ZN + pair * 256;
#pragma unroll 2
    for (int j8 = 0; j8 < 8; j8++) {
        v8us kb8;
#pragma unroll
        for (int e = 0; e < 8; e++) {
            int j = w * 64 + j8 * 8 + e;
            const float4* zrow = (const float4*)(ZS + ((long)pair * 256 + j) * 16);
            float4 z0 = zrow[0], z1 = zrow[1], z2 = zrow[2], z3 = zrow[3];
            float dot = z0.x * x0.x + z0.y * x0.y + z0.z * x0.z + z0.w * x0.w +
                        z1.x * x1.x + z1.y * x1.y + z1.z * x1.z + z1.w * x1.w +
                        z2.x * x2.x + z2.y * x2.y + z2.z * x2.z + z2.w * x2.w +
                        z3.x * x3.x + z3.y * x3.y + z3.z * x3.z + z3.w * x3.w;
            float d2 = fmaxf(znp[j] + xn - 2.f * dot, 0.f);
            float kv = sf2 * __expf(-0.5f * d2);
            mupart += cvp[j] * kv;
            unsigned int u = __float_as_uint(kv);
            u += 0x7fffu + ((u >> 16) & 1u);
            kb8[e] = (unsigned short)(u >> 16);
        }
        *(v8us*)&KbT[b][w * 64 + j8 * 8] = kb8;
    }
    mup[w][b] = mupart;
    __syncthreads();
    long kbase = ((long)pair * 1024 + bt * 64) * 256;
#pragma unroll
    for (int e = 0; e < 8; e++) {
        int c = e * 256 + t;
        int bb = c >> 5, cj = (c & 31) * 8;
        *(v8us*)(Kg + kbase + (long)bb * 256 + cj) = *(const v8us*)&KbT[bb][cj];
    }
    if (t < 64) {
        float mu = mup[0][t] + mup[1][t] + mup[2][t] + mup[3][t];
        out[(long)pair * 1024 + bt * 64 + t] = mu;
    }
}

// MFMA q kernel, 128-wide b-tiles: 1D grid, pair = idx&127 (XCD L2 locality for G)
#define KT2 264
__global__ __launch_bounds__(256) void k_kb4(const ushort_t* __restrict__ Kg,
                                             const ushort_t* __restrict__ Ghi,
                                             const ushort_t* __restrict__ Glo,
                                             const float* __restrict__ SF2, float* __restrict__ out) {
    int pair = blockIdx.x & 127;
    int bt = blockIdx.x >> 7;  // 0..7
    int h = pair >> 5;
    int t = threadIdx.x;
    int w = t >> 6;
    int lane = t & 63;
    int l31 = lane & 31, lhalf = lane >> 5;

    __shared__ __align__(16) ushort_t KbT[128][KT2];
    __shared__ float qpart[4][128];

    float sf2 = SF2[h];
    long kbase = ((long)pair * 1024 + bt * 128) * 256;
#pragma unroll
    for (int e = 0; e < 16; e++) {
        int c = e * 256 + t;
        int bb = c >> 5, cj = (c & 31) * 8;
        *(v8us*)&KbT[bb][cj] = *(const v8us*)(Kg + kbase + (long)bb * 256 + cj);
    }
    __syncthreads();

    v16f acc[2][4];
#pragma unroll
    for (int mt = 0; mt < 2; mt++)
#pragma unroll
        for (int nt = 0; nt < 4; nt++)
#pragma unroll
            for (int r = 0; r < 16; r++) acc[mt][nt][r] = 0.f;

    const ushort_t* GhiP = Ghi + (long)pair * 65536;
    const ushort_t* GloP = Glo + (long)pair * 65536;
#pragma unroll 2
    for (int k0 = 0; k0 < 256; k0 += 16) {
        v8bf bfr[4];
#pragma unroll
        for (int nt = 0; nt < 4; nt++)
            bfr[nt] = *(const v8bf*)&KbT[nt * 32 + l31][k0 + lhalf * 8];
#pragma unroll
        for (int mt = 0; mt < 2; mt++) {
            int i = w * 64 + mt * 32 + l31;
            v8bf ah = *(const v8bf*)(GhiP + (long)i * 256 + k0 + lhalf * 8);
            v8bf al = *(const v8bf*)(GloP + (long)i * 256 + k0 + lhalf * 8);
#pragma unroll
            for (int nt = 0; nt < 4; nt++) {
                acc[mt][nt] = __builtin_amdgcn_mfma_f32_32x32x16_bf16(ah, bfr[nt], acc[mt][nt], 0, 0, 0);
                acc[mt][nt] = __builtin_amdgcn_mfma_f32_32x32x16_bf16(al, bfr[nt], acc[mt][nt], 0, 0, 0);
            }
        }
    }

    float qp[4] = {0.f, 0.f, 0.f, 0.f};
#pragma unroll
    for (int mt = 0; mt < 2; mt++) {
#pragma unroll
        for (int nt = 0; nt < 4; nt++) {
            int b = nt * 32 + l31;
#pragma unroll
            for (int g = 0; g < 4; g++) {
                int ibase = w * 64 + mt * 32 + 8 * g + 4 * lhalf;
                v4us k4 = *(const v4us*)&KbT[b][ibase];
#pragma unroll
                for (int e = 0; e < 4; e++) {
                    float kv = bf2f(k4[e]);
                    qp[nt] += kv * acc[mt][nt][4 * g + e];
                }
            }
        }
    }
#pragma unroll
    for (int nt = 0; nt < 4; nt++) {
        qp[nt] += __shfl_down(qp[nt], 32, 64);
        if (lhalf == 0) qpart[w][nt * 32 + l31] = qp[nt];
    }
    __syncthreads();

    if (t < 128) {
        float q = qpart[0][t] + qpart[1][t] + qpart[2][t] + qpart[3][t];
        out[(long)H_ * O_ * B_ + (long)pair * 1024 + bt * 128 + t] = sf2 - q;
    }
}

// ---------------------------------------------------------------------------
extern "C" void kernel_launch(void* const* d_in, const int* in_sizes, int n_in,
                              void* d_out, int out_size, void* d_ws, size_t ws_size,
                              hipStream_t stream) {
    const float* x = (const float*)d_in[0];
    const float* z = (const float*)d_in[1];
    const float* u_mean = (const float*)d_in[2];
    const float* u_tril_vec = (const float*)d_in[3];
    const float* m_old = (const float*)d_in[4];
    const float* L_old = (const float*)d_in[5];
    const float* z_old = (const float*)d_in[6];
    const float* theta = (const float*)d_in[7];

    const long BIGSZ = (long)HO * M2 * M2;  // 8388608
    const long MSZ = (long)HO * M_ * M_;    // 2097152
    const long SO2 = (long)M2 * M2;

    float* ws = (float*)d_ws;
    long off = 0;
    float* BIG0 = ws + off; off += BIGSZ;  // KUU2 -> BLi -> AINV fp32
    float* BIG1 = ws + off; off += BIGSZ;  // LINVT h/l -> Y h/l -> Kg (part 1)
    float* BIG2 = ws + off; off += BIGSZ;  // Linv1|A1|Linv2|BLW -> AINV h/l -> Kg (part 2)
    float* BIG3 = ws + off; off += BIGSZ;  // WcT h/l -> G h/l
    float* ZS = ws + off; off += (long)HO * M2 * D_;
    float* XS = ws + off; off += (long)H_ * B_ * D_;
    float* ZN = ws + off; off += (long)HO * M2;
    float* XN = ws + off; off += (long)H_ * B_;
    float* MJ = ws + off; off += (long)HO * M2;
    float* CV = ws + off; off += (long)HO * M2;
    float* SF2v = ws + off; off += H_;

    float* KUU2 = BIG0;
    float* AINV = BIG0;
    float* Linv1 = BIG2;
    float* A1 = BIG2 + MSZ;
    float* A3 = BIG2 + 2 * MSZ;
    float* Linv2 = BIG2 + 2 * MSZ;
    float* BLW = BIG2 + 3 * MSZ;
    float* BLi = BIG0 + MSZ;         // over KUU2 (dead after choltri BR); NOT in BIG3
    ushort_t* LINVTh = (ushort_t*)BIG1;
    ushort_t* LINVTl = LINVTh + BIGSZ;
    ushort_t* AINVh = (ushort_t*)BIG2;
    ushort_t* AINVl = AINVh + BIGSZ;
    ushort_t* WcTh = (ushort_t*)BIG3;
    ushort_t* WcTl = WcTh + BIGSZ;
    ushort_t* Yh = (ushort_t*)BIG1;
    ushort_t* Yl = Yh + BIGSZ;
    ushort_t* Ghi = (ushort_t*)BIG3;
    ushort_t* Glo = Ghi + BIGSZ;
    ushort_t* Kg = (ushort_t*)BIG1;  // 64 MB spanning BIG1+BIG2 (both dead by then)
    const long BRoff = 128L * M2 + 128;

    // 1. preprocessing + kuu2 (fused)
    k_prekuu2<<<145, 256, 0, stream>>>(theta, x, z, z_old, SF2v, XS, XN, ZS, ZN, KUU2);
    // 2. chol TL + trinv -> Linv1
    k_choltri<<<HO, 256, 0, stream>>>(KUU2, SO2, M2, Linv1);
    // 3. A1 = Linv1@kuf ; A3 = Linv1@L_old (merged)
    k_a1a3<<<dim3(HO, 2), 256, 0, stream>>>(Linv1, KUU2, L_old, A1, A3);
    // 4. BLW = A1^T A3 ; KUU2_BR -= A1^T A1 ; m_joint (merged, y=0..2)
    k_blwschur<<<dim3(HO, 3), 256, 0, stream>>>(A1, A3, BLW, KUU2, Linv1, m_old, u_mean, MJ);
    // 5. chol BR + trinv -> Linv2 (over A3 slot — dead)
    k_choltri<<<HO, 256, 0, stream>>>(KUU2 + BRoff, SO2, M2, Linv2);
    // 6. BLi = -Linv2 @ (A1^T @ Linv1), T1 in LDS (KUU2 dead -> BIG0+MSZ)
    k_blicalc<<<HO, 256, 0, stream>>>(A1, Linv1, Linv2, BLi);
    // 7. LINVT + WcT planes (merged; BLi in BIG0, WcT in BIG3 — disjoint)
    k_split2<<<dim3(HO, 2), 256, 0, stream>>>(Linv1, BLi, Linv2, L_old, BLW, u_tril_vec,
                                              LINVTh, LINVTl, WcTh, WcTl);
    // 8. zero CV for fused matvec
    hipMemsetAsync(CV, 0, (long)HO * M2 * sizeof(float), stream);
    // 9. AINV = LINVT (.) LINVT -> fp32 (BIG0; BLi dead) + planes (BIG2) + CV fused
    k_bmmx<1><<<dim3(HO, 3), 256, 0, stream>>>(LINVTh, LINVTl, LINVTh, LINVTl,
                                               AINV, AINVh, AINVl, nullptr, 1, 1.f, MJ, CV);
    // 10. Y = AINV @ Wc -> Y planes (BIG1; LINVT dead)
    k_bmmx<0><<<dim3(HO, 4), 256, 0, stream>>>(AINVh, AINVl, WcTh, WcTl,
                                               nullptr, Yh, Yl, nullptr, 2, 1.f, nullptr, nullptr);
    // 11. G = AINV - Y Y^T -> G planes (BIG3; WcT dead)
    k_bmmx<1><<<dim3(HO, 3), 256, 0, stream>>>(Yh, Yl, Yh, Yl,
                                               nullptr, Ghi, Glo, AINV, 0, -1.f, nullptr, nullptr);
    // 12. K build + mu (Kg over BIG1+BIG2 — Y and AINV planes dead)
    k_kbuild<<<dim3(16, HO), 256, 0, stream>>>(ZS, ZN, XS, XN, SF2v, CV, Kg, (float*)d_out);
    // 13. MFMA q/var, 128-wide b-tiles
    k_kb4<<<1024, 256, 0, stream>>>(Kg, Ghi, Glo, SF2v, (float*)d_out);
}

// Round 13
// 677.626 us; speedup vs baseline: 1.3978x; 1.1008x over previous
//
#include <hip/hip_runtime.h>

#define H_ 4
#define O_ 32
#define HO 128
#define M_ 128
#define M2 256
#define D_ 16
#define B_ 1024
#define JIT 1e-4f

typedef unsigned short ushort_t;
typedef __bf16 v8bf __attribute__((ext_vector_type(8)));
typedef float v16f __attribute__((ext_vector_type(16)));
typedef unsigned short v8us __attribute__((ext_vector_type(8)));
typedef unsigned short v4us __attribute__((ext_vector_type(4)));

__device__ inline void splitbf(float v, ushort_t& hb, ushort_t& lb) {
    unsigned int u = __float_as_uint(v);
    hb = (ushort_t)(u >> 16);
    float hf = __uint_as_float((unsigned int)hb << 16);
    float r = v - hf;
    lb = (ushort_t)(__float_as_uint(r) >> 16);
}
__device__ inline float bf2f(ushort_t u) { return __uint_as_float((unsigned int)u << 16); }

// ---------------------------------------------------------------------------
// merged preprocessing + kuu2
__global__ __launch_bounds__(256) void k_prekuu2(const float* __restrict__ theta,
                                                 const float* __restrict__ x,
                                                 const float* __restrict__ z,
                                                 const float* __restrict__ z_old,
                                                 float* __restrict__ SF2,
                                                 float* __restrict__ XS, float* __restrict__ XN,
                                                 float* __restrict__ ZS, float* __restrict__ ZN,
                                                 float* __restrict__ K2) {
    int bb = blockIdx.x, t = threadIdx.x;
    __shared__ float zs[M2][D_];
    __shared__ float zn[M2];
    __shared__ float ls[D_];
    if (bb == 144) {
        if (t < H_) SF2[t] = __expf(theta[t * (D_ + 1)]);
        return;
    }
    if (bb >= 128) {
        int j = (bb - 128) * 256 + t;
        int h = j >> 10, b = j & 1023;
        if (t < D_) ls[t] = __expf(-theta[h * (D_ + 1) + 1 + t]);
        __syncthreads();
        float s = 0.f;
#pragma unroll
        for (int d = 0; d < D_; d++) {
            float v = x[b * D_ + d] * ls[d];
            XS[(long)j * D_ + d] = v;
            s += v * v;
        }
        XN[j] = s;
        return;
    }
    int pair = bb, h = pair >> 5, o = pair & 31, i = t;
    if (t < D_) ls[t] = __expf(-theta[h * (D_ + 1) + 1 + t]);
    __syncthreads();
    const float* src = (i < M_) ? (z_old + ((long)o * M_ + i) * D_)
                                : (z + ((long)o * M_ + (i - M_)) * D_);
    float s = 0.f;
#pragma unroll
    for (int d = 0; d < D_; d++) {
        float v = src[d] * ls[d];
        zs[i][d] = v;
        ZS[((long)pair * M2 + i) * D_ + d] = v;
        s += v * v;
    }
    zn[i] = s;
    ZN[pair * M2 + i] = s;
    __syncthreads();
    float sf2 = __expf(theta[h * (D_ + 1)]);
    float my[D_];
#pragma unroll
    for (int d = 0; d < D_; d++) my[d] = zs[i][d];
    float myn = zn[i];
    for (int q = 0; q < M2; q++) {
        float dot = 0.f;
#pragma unroll
        for (int d = 0; d < D_; d++) dot += zs[q][d] * my[d];
        float d2 = fmaxf(zn[q] + myn - 2.f * dot, 0.f);
        float v = sf2 * __expf(-0.5f * d2);
        if (q == i) v += JIT;
        K2[(long)pair * M2 * M2 + (long)q * M2 + i] = v;
    }
}

// shared chol(128)+trinv body (R10/R12 loop-based version)
__device__ __forceinline__ void choltri_body(const float* __restrict__ S, int ldsrc,
                                             float* __restrict__ Li, long b1, int t,
                                             float* Ap, float* rsq,
                                             float (*Ld)[64][66], float (*Wd)[64][66],
                                             float (*LB)[66], float (*Tt)[66]) {
    for (int e = t; e < M_ * (M_ + 1) / 2; e += 256) {
        int i = (int)((sqrtf(8.f * e + 1.f) - 1.f) * 0.5f);
        while ((i + 1) * (i + 2) / 2 <= e) i++;
        while (i * (i + 1) / 2 > e) i--;
        int j = e - i * (i + 1) / 2;
        Ap[e] = S[(long)i * ldsrc + j];
    }
    int pi[3], pj[3];
#pragma unroll
    for (int u = 0; u < 3; u++) {
        int p = t + u * 256;
        if (p < 528) {
            int i = (int)((sqrtf(8.f * p + 1.f) - 1.f) * 0.5f);
            while ((i + 1) * (i + 2) / 2 <= p) i++;
            while (i * (i + 1) / 2 > p) i--;
            pi[u] = i;
            pj[u] = p - i * (i + 1) / 2;
        } else {
            pi[u] = -1;
            pj[u] = 0;
        }
    }
    __syncthreads();

    for (int kb = 0; kb < 4; kb++) {
        int c0 = kb * 32;
        for (int k = 0; k < 32; k++) {
            int kc = c0 + k;
            float rd = 1.f / Ap[kc * (kc + 1) / 2 + kc];
#pragma unroll
            for (int u = 0; u < 3; u++) {
                int i = pi[u], j = pj[u];
                if (i > k && j > k) {
                    int gi = c0 + i, gj = c0 + j;
                    Ap[gi * (gi + 1) / 2 + gj] -=
                        Ap[gi * (gi + 1) / 2 + kc] * Ap[gj * (gj + 1) / 2 + kc] * rd;
                }
            }
            __syncthreads();
        }
        if (t < 32) {
            int g = c0 + t;
            rsq[t] = rsqrtf(Ap[g * (g + 1) / 2 + g]);
        }
        __syncthreads();
#pragma unroll
        for (int u = 0; u < 3; u++) {
            int i = pi[u], j = pj[u];
            if (i >= 0) {
                int gi = c0 + i, gj = c0 + j;
                Ap[gi * (gi + 1) / 2 + gj] *= rsq[j];
            }
        }
        __syncthreads();

        int R = M_ - c0 - 32;
        if (R > 0) {
            if (t < R) {
                int gi = c0 + 32 + t;
                int base = gi * (gi + 1) / 2 + c0;
                float xr[32];
#pragma unroll
                for (int j = 0; j < 32; j++) xr[j] = Ap[base + j];
#pragma unroll
                for (int q = 0; q < 32; q++) {
                    float xq = xr[q] * rsq[q];
                    xr[q] = xq;
#pragma unroll
                    for (int j = q + 1; j < 32; j++)
                        xr[j] -= xq * Ap[(c0 + j) * (c0 + j + 1) / 2 + c0 + q];
                }
#pragma unroll
                for (int j = 0; j < 32; j++) Ap[base + j] = xr[j];
            }
            __syncthreads();
            int nb = R >> 2;
            int ntile = nb * (nb + 1) / 2;
            for (int tp = t; tp < ntile; tp += 256) {
                int bi = (int)((sqrtf(8.f * tp + 1.f) - 1.f) * 0.5f);
                while ((bi + 1) * (bi + 2) / 2 <= tp) bi++;
                while (bi * (bi + 1) / 2 > tp) bi--;
                int bj = tp - bi * (bi + 1) / 2;
                int i0 = c0 + 32 + bi * 4, j0 = c0 + 32 + bj * 4;
                float acc[4][4] = {};
                for (int k = 0; k < 32; k++) {
                    float a[4], b[4];
#pragma unroll
                    for (int q = 0; q < 4; q++) a[q] = Ap[(i0 + q) * (i0 + q + 1) / 2 + c0 + k];
#pragma unroll
                    for (int r = 0; r < 4; r++) b[r] = Ap[(j0 + r) * (j0 + r + 1) / 2 + c0 + k];
#pragma unroll
                    for (int q = 0; q < 4; q++)
#pragma unroll
                        for (int r = 0; r < 4; r++) acc[q][r] += a[q] * b[r];
                }
#pragma unroll
                for (int q = 0; q < 4; q++)
#pragma unroll
                    for (int r = 0; r < 4; r++) {
                        int gi = i0 + q, gj = j0 + r;
                        if (gj <= gi) Ap[gi * (gi + 1) / 2 + gj] -= acc[q][r];
                    }
            }
            __syncthreads();
        }
    }

    for (int e = t; e < 8192; e += 256) {
        int g = e >> 12, i = (e >> 6) & 63, j = e & 63;
        int gi = g * 64 + i, gj = g * 64 + j;
        Ld[g][i][j] = (j <= i) ? Ap[gi * (gi + 1) / 2 + gj] : 0.f;
    }
    for (int e = t; e < 4096; e += 256) {
        int i = e >> 6, j = e & 63;
        int gi = 64 + i;
        LB[i][j] = Ap[gi * (gi + 1) / 2 + j];
    }
    __syncthreads();
    if (t < 128) {
        int g = t >> 6, c = t & 63;
        for (int i = 0; i < 64; i++) {
            float acc = (i == c) ? 1.f : 0.f;
            for (int j = 0; j < i; j++) acc -= Ld[g][i][j] * Wd[g][j][c];
            Wd[g][i][c] = acc / Ld[g][i][i];
        }
    }
    __syncthreads();
    int ti = t >> 4, tj = t & 15;
    float acc[4][4] = {};
    for (int kk = 0; kk < 64; kk++) {
        float a[4], b[4];
#pragma unroll
        for (int q = 0; q < 4; q++) a[q] = LB[ti * 4 + q][kk];
#pragma unroll
        for (int r = 0; r < 4; r++) b[r] = Wd[0][kk][tj * 4 + r];
#pragma unroll
        for (int q = 0; q < 4; q++)
#pragma unroll
            for (int r = 0; r < 4; r++) acc[q][r] += a[q] * b[r];
    }
#pragma unroll
    for (int q = 0; q < 4; q++)
#pragma unroll
        for (int r = 0; r < 4; r++) Tt[ti * 4 + q][tj * 4 + r] = acc[q][r];
    __syncthreads();
    float xo[4][4] = {};
    for (int kk = 0; kk < 64; kk++) {
        float a[4], b[4];
#pragma unroll
        for (int q = 0; q < 4; q++) a[q] = Wd[1][ti * 4 + q][kk];
#pragma unroll
        for (int r = 0; r < 4; r++) b[r] = Tt[kk][tj * 4 + r];
#pragma unroll
        for (int q = 0; q < 4; q++)
#pragma unroll
            for (int r = 0; r < 4; r++) xo[q][r] -= a[q] * b[r];
    }
#pragma unroll
    for (int q = 0; q < 4; q++)
#pragma unroll
        for (int r = 0; r < 4; r++)
            Li[b1 + (long)(64 + ti * 4 + q) * 128 + tj * 4 + r] = xo[q][r];
    for (int e = t; e < 4096; e += 256) {
        int i = e >> 6, j = e & 63;
        Li[b1 + (long)i * 128 + j] = Wd[0][i][j];
        Li[b1 + (long)(64 + i) * 128 + 64 + j] = Wd[1][i][j];
        Li[b1 + (long)i * 128 + 64 + j] = 0.f;
    }
}

// chol TL + co-scheduled WcT part A (UT BR quadrant, zeros, L_old part)
__global__ __launch_bounds__(256) void k_choltri_tl(const float* __restrict__ src,
                                                    float* __restrict__ Li,
                                                    const float* __restrict__ L_old,
                                                    const float* __restrict__ vec,
                                                    ushort_t* __restrict__ WTh,
                                                    ushort_t* __restrict__ WTl) {
    int bb = blockIdx.x, t = threadIdx.x;
    __shared__ float Ap[M_ * (M_ + 1) / 2];
    __shared__ float rsq[32];
    __shared__ float Ld[2][64][66], Wd[2][64][66], LB[64][66], Tt[64][66];
    if (bb < 128) {
        choltri_body(src + (long)bb * ((long)M2 * M2), M2, Li, (long)bb * 16384, t,
                     Ap, rsq, Ld, Wd, LB, Tt);
        return;
    }
    // co-path: WcT part A for pair bb-128
    int pair = bb - 128, o = pair & 31;
    long b2 = (long)pair * 65536;
    float* vs = Ap;  // alias (8256 floats)
    float(*tile)[33] = (float(*)[33])Tt;
    for (int e = t; e < M_ * (M_ + 1) / 2; e += 256) vs[e] = vec[(long)o * (M_ * (M_ + 1) / 2) + e];
    __syncthreads();
    for (int e = t; e < 16384; e += 256) {
        int n = e >> 7, k = e & 127;
        float v = (k >= n) ? vs[k * (k + 1) / 2 + n] : 0.f;
        ushort_t hb, lb;
        splitbf(v, hb, lb);
        long a = b2 + (long)(128 + n) * 256 + 128 + k;
        WTh[a] = hb;
        WTl[a] = lb;
    }
    for (int e = t; e < 16384; e += 256) {
        int n = e >> 7, k = e & 127;
        long a = b2 + (long)(128 + n) * 256 + k;
        WTh[a] = 0;
        WTl[a] = 0;
    }
    const float* sp = L_old + (long)o * 16384;
    int tx = t & 31, ty = t >> 5;
    for (int bi = 0; bi < 4; bi++)
        for (int bj = 0; bj < 4; bj++) {
            __syncthreads();
            for (int r = ty; r < 32; r += 8)
                tile[r][tx] = sp[(long)(bi * 32 + r) * 128 + bj * 32 + tx];
            __syncthreads();
            for (int r = ty; r < 32; r += 8) {
                ushort_t hb, lb;
                splitbf(tile[tx][r], hb, lb);
                long a = b2 + (long)(bj * 32 + r) * 256 + bi * 32 + tx;
                WTh[a] = hb;
                WTl[a] = lb;
            }
        }
}

// chol BR + co-scheduled: T1 = A1^T Linv1 (blocks 128-255), LINVT zeros+Linv1 part
// (256-383), WcT BLW part (384-511)
__global__ __launch_bounds__(256) void k_choltri_br(const float* __restrict__ src,
                                                    float* __restrict__ Li,
                                                    const float* __restrict__ A1,
                                                    const float* __restrict__ Linv1,
                                                    float* __restrict__ T1g,
                                                    const float* __restrict__ BLW,
                                                    ushort_t* __restrict__ LTh,
                                                    ushort_t* __restrict__ LTl,
                                                    ushort_t* __restrict__ WTh,
                                                    ushort_t* __restrict__ WTl) {
    int bb = blockIdx.x, t = threadIdx.x;
    __shared__ float Ap[M_ * (M_ + 1) / 2];
    __shared__ float rsq[32];
    __shared__ float Ld[2][64][66], Wd[2][64][66], LB[64][66], Tt[64][66];
    if (bb < 128) {
        choltri_body(src + (long)bb * ((long)M2 * M2), M2, Li, (long)bb * 16384, t,
                     Ap, rsq, Ld, Wd, LB, Tt);
        return;
    }
    if (bb < 256) {
        // T1 = A1^T @ Linv1 -> T1g (per-pair stride 65536)
        int pair = bb - 128;
        long b1 = (long)pair * 16384;
        float(*As)[132] = (float(*)[132])Ld;
        float(*Bs)[132] = ((float(*)[132])Ld) + 16;
        const float* Apt = A1 + b1;
        const float* Bpt = Linv1 + b1;
        float* Cp = T1g + (long)pair * 65536;
        int tx = t & 15, ty = t >> 4;
        float acc[8][8] = {};
        for (int kt = 0; kt < M_; kt += 16) {
#pragma unroll
            for (int q = 0; q < 8; q++) {
                int e = q * 256 + t;
                int kk = e >> 7, m = e & 127;
                As[kk][m] = Apt[(long)(kt + kk) * 128 + m];
                Bs[kk][m] = Bpt[(long)(kt + kk) * 128 + m];
            }
            __syncthreads();
#pragma unroll
            for (int kk = 0; kk < 16; kk++) {
                float a[8], b[8];
#pragma unroll
                for (int q = 0; q < 8; q++) { a[q] = As[kk][ty + 16 * q]; b[q] = Bs[kk][tx + 16 * q]; }
#pragma unroll
                for (int q = 0; q < 8; q++)
#pragma unroll
                    for (int r = 0; r < 8; r++) acc[q][r] += a[q] * b[r];
            }
            __syncthreads();
        }
#pragma unroll
        for (int q = 0; q < 8; q++)
#pragma unroll
            for (int r = 0; r < 8; r++)
                Cp[(long)(ty + 16 * q) * 128 + tx + 16 * r] = acc[q][r];
        return;
    }
    if (bb < 384) {
        // LINVT zeros (rows 128+, cols<128) + Linv1 part
        int pair = bb - 256;
        long b2 = (long)pair * 65536, b1 = (long)pair * 16384;
        float(*tile)[33] = (float(*)[33])Tt;
        for (int e = t; e < 16384; e += 256) {
            int n = e >> 7, k = e & 127;
            long a = b2 + (long)(128 + n) * 256 + k;
            LTh[a] = 0;
            LTl[a] = 0;
        }
        const float* sp = Linv1 + b1;
        int tx = t & 31, ty = t >> 5;
        for (int bi = 0; bi < 4; bi++)
            for (int bj = 0; bj < 4; bj++) {
                __syncthreads();
                for (int r = ty; r < 32; r += 8)
                    tile[r][tx] = sp[(long)(bi * 32 + r) * 128 + bj * 32 + tx];
                __syncthreads();
                for (int r = ty; r < 32; r += 8) {
                    ushort_t hb, lb;
                    splitbf(tile[tx][r], hb, lb);
                    long a = b2 + (long)(bj * 32 + r) * 256 + bi * 32 + tx;
                    LTh[a] = hb;
                    LTl[a] = lb;
                }
            }
        return;
    }
    {
        // WcT part B: BLW transposed into cols 128.. rows <128
        int pair = bb - 384;
        long b2 = (long)pair * 65536, b1 = (long)pair * 16384;
        float(*tile)[33] = (float(*)[33])Tt;
        const float* sp = BLW + b1;
        int tx = t & 31, ty = t >> 5;
        for (int bi = 0; bi < 4; bi++)
            for (int bj = 0; bj < 4; bj++) {
                __syncthreads();
                for (int r = ty; r < 32; r += 8)
                    tile[r][tx] = sp[(long)(bi * 32 + r) * 128 + bj * 32 + tx];
                __syncthreads();
                for (int r = ty; r < 32; r += 8) {
                    ushort_t hb, lb;
                    splitbf(tile[tx][r], hb, lb);
                    long a = b2 + (long)(bj * 32 + r) * 256 + 128 + bi * 32 + tx;
                    WTh[a] = hb;
                    WTl[a] = lb;
                }
            }
    }
}

// merged A1/A3: y=0: A1 = Linv1 @ kuf(KUU2 TR); y=1: A3 = Linv1 @ L_old
__global__ __launch_bounds__(256) void k_a1a3(const float* __restrict__ Linv1,
                                              const float* __restrict__ KUU2,
                                              const float* __restrict__ L_old,
                                              float* __restrict__ A1, float* __restrict__ A3) {
    int pair = blockIdx.x, y = blockIdx.y, o = pair & 31;
    const float* Ap = Linv1 + (long)pair * 16384;
    const float* Bp = y ? (L_old + (long)o * 16384) : (KUU2 + (long)pair * 65536 + 128);
    int ldb = y ? 128 : 256;
    float* Cp = (y ? A3 : A1) + (long)pair * 16384;
    int t = threadIdx.x, tx = t & 15, ty = t >> 4;
    __shared__ float As[16][132], Bs[16][132];
    float acc[8][8] = {};
    for (int kt = 0; kt < M_; kt += 16) {
#pragma unroll
        for (int q = 0; q < 8; q++) {
            int e = q * 256 + t;
            int m = e >> 4, kk = e & 15;
            As[kk][m] = Ap[(long)m * 128 + kt + kk];
            int kk2 = e >> 7, n = e & 127;
            Bs[kk2][n] = Bp[(long)(kt + kk2) * ldb + n];
        }
        __syncthreads();
#pragma unroll
        for (int kk = 0; kk < 16; kk++) {
            float a[8], b[8];
#pragma unroll
            for (int q = 0; q < 8; q++) { a[q] = As[kk][ty + 16 * q]; b[q] = Bs[kk][tx + 16 * q]; }
#pragma unroll
            for (int q = 0; q < 8; q++)
#pragma unroll
                for (int r = 0; r < 8; r++) acc[q][r] += a[q] * b[r];
        }
        __syncthreads();
    }
#pragma unroll
    for (int q = 0; q < 8; q++)
#pragma unroll
        for (int r = 0; r < 8; r++)
            Cp[(long)(ty + 16 * q) * 128 + tx + 16 * r] = acc[q][r];
}

// merged: y=0: BLW = A1^T A3; y=1: KUU2_BR -= A1^T A1; y=2: m_joint + CV zero
__global__ __launch_bounds__(256) void k_blwschur(const float* __restrict__ A1,
                                                  const float* __restrict__ A3,
                                                  float* __restrict__ BLW,
                                                  float* __restrict__ KUU2,
                                                  const float* __restrict__ Linv1,
                                                  const float* __restrict__ m_old,
                                                  const float* __restrict__ u_mean,
                                                  float* __restrict__ MJ,
                                                  float* __restrict__ CV) {
    int pair = blockIdx.x, y = blockIdx.y, o = pair & 31;
    int t = threadIdx.x;
    if (y == 2) {
        CV[pair * 256 + t] = 0.f;
        __shared__ float mo[128], a2[128];
        if (t < 128) mo[t] = m_old[o * 128 + t];
        __syncthreads();
        if (t < 128) {
            const float* Lr = Linv1 + (long)pair * 16384 + (long)t * 128;
            float acc = 0.f;
            for (int j = 0; j <= t; j++) acc += Lr[j] * mo[j];
            a2[t] = acc;
        }
        __syncthreads();
        if (t < 128) {
            float m = 0.f;
            for (int i = 0; i < 128; i++) m += A1[(long)pair * 16384 + (long)i * 128 + t] * a2[i];
            MJ[pair * 256 + t] = mo[t];
            MJ[pair * 256 + 128 + t] = m + u_mean[o * 128 + t];
        }
        return;
    }
    const float* Ap = A1 + (long)pair * 16384;
    const float* Bp = (y ? A1 : A3) + (long)pair * 16384;
    float* Cp;
    int ldc;
    if (y) { Cp = KUU2 + (long)pair * 65536 + 128L * 256 + 128; ldc = 256; }
    else   { Cp = BLW + (long)pair * 16384; ldc = 128; }
    int tx = t & 15, ty = t >> 4;
    __shared__ float As[16][132], Bs[16][132];
    float acc[8][8] = {};
    for (int kt = 0; kt < M_; kt += 16) {
#pragma unroll
        for (int q = 0; q < 8; q++) {
            int e = q * 256 + t;
            int kk = e >> 7, m = e & 127;
            As[kk][m] = Ap[(long)(kt + kk) * 128 + m];
            Bs[kk][m] = Bp[(long)(kt + kk) * 128 + m];
        }
        __syncthreads();
#pragma unroll
        for (int kk = 0; kk < 16; kk++) {
            float a[8], b[8];
#pragma unroll
            for (int q = 0; q < 8; q++) { a[q] = As[kk][ty + 16 * q]; b[q] = Bs[kk][tx + 16 * q]; }
#pragma unroll
            for (int q = 0; q < 8; q++)
#pragma unroll
                for (int r = 0; r < 8; r++) acc[q][r] += a[q] * b[r];
        }
        __syncthreads();
    }
#pragma unroll
    for (int q = 0; q < 8; q++)
#pragma unroll
        for (int r = 0; r < 8; r++) {
            long idx = (long)(ty + 16 * q) * ldc + tx + 16 * r;
            if (y) Cp[idx] -= acc[q][r];
            else Cp[idx] = acc[q][r];
        }
}

// BLi = -Linv2 @ T1g; write LINVT BLi-part planes (transposed) + Linv2 part
__global__ __launch_bounds__(256) void k_blicalc2(const float* __restrict__ Linv2,
                                                  const float* __restrict__ T1g,
                                                  ushort_t* __restrict__ LTh,
                                                  ushort_t* __restrict__ LTl) {
    int pair = blockIdx.x, t = threadIdx.x, tx = t & 15, ty = t >> 4;
    long b1 = (long)pair * 16384, b2 = (long)pair * 65536;
    __shared__ float T1s[128][129];
    __shared__ float As[16][132], Bs[16][132];
    const float* Apt = Linv2 + b1;
    const float* Bpt = T1g + (long)pair * 65536;
    float acc[8][8] = {};
    for (int kt = 0; kt < M_; kt += 16) {
#pragma unroll
        for (int q = 0; q < 8; q++) {
            int e = q * 256 + t;
            int m = e >> 4, kk = e & 15;
            As[kk][m] = Apt[(long)m * 128 + kt + kk];
            int kk2 = e >> 7, n = e & 127;
            Bs[kk2][n] = Bpt[(long)(kt + kk2) * 128 + n];
        }
        __syncthreads();
#pragma unroll
        for (int kk = 0; kk < 16; kk++) {
            float a[8], b[8];
#pragma unroll
            for (int q = 0; q < 8; q++) { a[q] = As[kk][ty + 16 * q]; b[q] = Bs[kk][tx + 16 * q]; }
#pragma unroll
            for (int q = 0; q < 8; q++)
#pragma unroll
                for (int r = 0; r < 8; r++) acc[q][r] += a[q] * b[r];
        }
        __syncthreads();
    }
#pragma unroll
    for (int q = 0; q < 8; q++)
#pragma unroll
        for (int r = 0; r < 8; r++) T1s[ty + 16 * q][tx + 16 * r] = -acc[q][r];
    __syncthreads();
    // LINVT[j][128+i] = BLi[i][j]
    for (int e = t; e < 16384; e += 256) {
        int j = e >> 7, i = e & 127;
        ushort_t hb, lb;
        splitbf(T1s[i][j], hb, lb);
        long a = b2 + (long)j * 256 + 128 + i;
        LTh[a] = hb;
        LTl[a] = lb;
    }
    __syncthreads();
    // load Linv2 and write LINVT[128+n][128+k] = Linv2[k][n]
    for (int e = t; e < 16384; e += 256) {
        int i = e >> 7, j = e & 127;
        T1s[i][j] = Apt[(long)i * 128 + j];
    }
    __syncthreads();
    for (int e = t; e < 16384; e += 256) {
        int n = e >> 7, k = e & 127;
        ushort_t hb, lb;
        splitbf(T1s[k][n], hb, lb);
        long a = b2 + (long)(128 + n) * 256 + 128 + k;
        LTh[a] = hb;
        LTl[a] = lb;
    }
}

// split-bf16 MFMA batched GEMM: C = alpha*(Ah+Al)(Bh+Bl)^T [+ Dm]
// optional fused matvec: CVat += C @ MJv
#define BSTR 56
template <int TILES3>
__global__ __launch_bounds__(256) void k_bmmx(const ushort_t* __restrict__ Ah,
                                              const ushort_t* __restrict__ Al,
                                              const ushort_t* __restrict__ Bh,
                                              const ushort_t* __restrict__ Bl,
                                              float* __restrict__ Cf,
                                              ushort_t* __restrict__ Chi,
                                              ushort_t* __restrict__ Clo,
                                              const float* __restrict__ Dm,
                                              int kLoMode, float alpha,
                                              const float* __restrict__ MJv,
                                              float* __restrict__ CVat) {
    int pair = blockIdx.x;
    long base = (long)pair * 65536;
    int I0, J0, mir = 0;
    if (TILES3) {
        int qb = blockIdx.y;
        I0 = (qb == 0) ? 0 : 128;
        J0 = (qb == 2) ? 0 : I0;
        mir = (qb == 2);
    } else {
        I0 = (blockIdx.y >> 1) * 128;
        J0 = (blockIdx.y & 1) * 128;
    }
    int k0 = (kLoMode == 1) ? max(I0, J0) : (kLoMode == 2) ? J0 : 0;
    int t = threadIdx.x;
    int w = t >> 6, lane = t & 63;
    int l31 = lane & 31, lhalf = lane >> 5;
    int wy = w >> 1, wx = w & 1;

    __shared__ __align__(16) ushort_t AsH[128][BSTR], AsL[128][BSTR];
    __shared__ __align__(16) ushort_t BsH[128][BSTR], BsL[128][BSTR];

    v16f acc[2][2];
#pragma unroll
    for (int mt = 0; mt < 2; mt++)
#pragma unroll
        for (int nt = 0; nt < 2; nt++)
#pragma unroll
            for (int r = 0; r < 16; r++) acc[mt][nt][r] = 0.f;

    for (int kt = k0; kt < 256; kt += 32) {
        __syncthreads();
#pragma unroll
        for (int u = 0; u < 2; u++) {
            int idx = u * 256 + t;
            int m = idx >> 2, kc = (idx & 3) * 8;
            long arow = base + (long)(I0 + m) * 256 + kt + kc;
            long brow = base + (long)(J0 + m) * 256 + kt + kc;
            *(v8us*)&AsH[m][kc] = *(const v8us*)(Ah + arow);
            *(v8us*)&AsL[m][kc] = *(const v8us*)(Al + arow);
            *(v8us*)&BsH[m][kc] = *(const v8us*)(Bh + brow);
            *(v8us*)&BsL[m][kc] = *(const v8us*)(Bl + brow);
        }
        __syncthreads();
#pragma unroll
        for (int ks = 0; ks < 2; ks++) {
            int ko = ks * 16 + lhalf * 8;
            v8bf ah[2], al[2], bh[2], bl[2];
#pragma unroll
            for (int mt = 0; mt < 2; mt++) {
                int r = wy * 64 + mt * 32 + l31;
                ah[mt] = *(const v8bf*)&AsH[r][ko];
                al[mt] = *(const v8bf*)&AsL[r][ko];
            }
#pragma unroll
            for (int nt = 0; nt < 2; nt++) {
                int r = wx * 64 + nt * 32 + l31;
                bh[nt] = *(const v8bf*)&BsH[r][ko];
                bl[nt] = *(const v8bf*)&BsL[r][ko];
            }
#pragma unroll
            for (int mt = 0; mt < 2; mt++)
#pragma unroll
                for (int nt = 0; nt < 2; nt++) {
                    acc[mt][nt] = __builtin_amdgcn_mfma_f32_32x32x16_bf16(ah[mt], bh[nt], acc[mt][nt], 0, 0, 0);
                    acc[mt][nt] = __builtin_amdgcn_mfma_f32_32x32x16_bf16(ah[mt], bl[nt], acc[mt][nt], 0, 0, 0);
                    acc[mt][nt] = __builtin_amdgcn_mfma_f32_32x32x16_bf16(al[mt], bh[nt], acc[mt][nt], 0, 0, 0);
                }
        }
    }

    float mjc[2] = {0.f, 0.f};
    float cvmir[2] = {0.f, 0.f};
    if (MJv) {
#pragma unroll
        for (int nt = 0; nt < 2; nt++)
            mjc[nt] = MJv[(long)pair * 256 + J0 + wx * 64 + nt * 32 + l31];
    }
#pragma unroll
    for (int mt = 0; mt < 2; mt++) {
#pragma unroll
        for (int r = 0; r < 16; r++) {
            int row = I0 + wy * 64 + mt * 32 + 8 * (r >> 2) + 4 * lhalf + (r & 3);
            float rowsum = 0.f;
            float mjrow = 0.f;
            if (MJv && mir) mjrow = MJv[(long)pair * 256 + row];
#pragma unroll
            for (int nt = 0; nt < 2; nt++) {
                int col = J0 + wx * 64 + nt * 32 + l31;
                long idx = base + (long)row * 256 + col;
                float v = alpha * acc[mt][nt][r];
                if (Dm) v += Dm[idx];
                ushort_t hb, lb;
                splitbf(v, hb, lb);
                if (Cf) Cf[idx] = v;
                if (Chi) { Chi[idx] = hb; Clo[idx] = lb; }
                if (mir) {
                    long idxT = base + (long)col * 256 + row;
                    if (Cf) Cf[idxT] = v;
                    if (Chi) { Chi[idxT] = hb; Clo[idxT] = lb; }
                }
                if (MJv) {
                    rowsum += v * mjc[nt];
                    if (mir) cvmir[nt] += v * mjrow;
                }
            }
            if (MJv) {
#pragma unroll
                for (int m = 1; m < 32; m <<= 1) rowsum += __shfl_xor(rowsum, m, 64);
                if (l31 == 0) atomicAdd(&CVat[(long)pair * 256 + row], rowsum);
            }
        }
    }
    if (MJv && mir) {
#pragma unroll
        for (int nt = 0; nt < 2; nt++)
            atomicAdd(&CVat[(long)pair * 256 + J0 + wx * 64 + nt * 32 + l31], cvmir[nt]);
    }
}

#define KTP 280
// K build: per (bt, pair): compute K tile (fp32 kv), write bf16 K to global, fold mu
__global__ __launch_bounds__(256) void k_kbuild(const float* __restrict__ ZS, const float* __restrict__ ZN,
                                                const float* __restrict__ XS, const float* __restrict__ XN,
                                                const float* __restrict__ SF2, const float* __restrict__ CV,
                                                ushort_t* __restrict__ Kg, float* __restrict__ out) {
    int bt = blockIdx.x;
    int pair = blockIdx.y;
    int h = pair >> 5;
    int t = threadIdx.x;
    int w = t >> 6;
    int b = t & 63;

    __shared__ __align__(16) ushort_t KbT[64][KTP];
    __shared__ float mup[4][64];

    float sf2 = SF2[h];
    long bg = (long)h * B_ + bt * 64 + b;
    const float4* xrow = (const float4*)(XS + bg * 16);
    float4 x0 = xrow[0], x1 = xrow[1], x2 = xrow[2], x3 = xrow[3];
    float xn = XN[bg];
    float mupart = 0.f;
    const float* cvp = CV + pair * 256;
    const float* znp = ZN + pair * 256;
#pragma unroll 2
    for (int j8 = 0; j8 < 8; j8++) {
        v8us kb8;
#pragma unroll
        for (int e = 0; e < 8; e++) {
            int j = w * 64 + j8 * 8 + e;
            const float4* zrow = (const float4*)(ZS + ((long)pair * 256 + j) * 16);
            float4 z0 = zrow[0], z1 = zrow[1], z2 = zrow[2], z3 = zrow[3];
            float dot = z0.x * x0.x + z0.y * x0.y + z0.z * x0.z + z0.w * x0.w +
                        z1.x * x1.x + z1.y * x1.y + z1.z * x1.z + z1.w * x1.w +
                        z2.x * x2.x + z2.y * x2.y + z2.z * x2.z + z2.w * x2.w +
                        z3.x * x3.x + z3.y * x3.y + z3.z * x3.z + z3.w * x3.w;
            float d2 = fmaxf(znp[j] + xn - 2.f * dot, 0.f);
            float kv = sf2 * __expf(-0.5f * d2);
            mupart += cvp[j] * kv;
            unsigned int u = __float_as_uint(kv);
            u += 0x7fffu + ((u >> 16) & 1u);
            kb8[e] = (unsigned short)(u >> 16);
        }
        *(v8us*)&KbT[b][w * 64 + j8 * 8] = kb8;
    }
    mup[w][b] = mupart;
    __syncthreads();
    long kbase = ((long)pair * 1024 + bt * 64) * 256;
#pragma unroll
    for (int e = 0; e < 8; e++) {
        int c = e * 256 + t;
        int bb = c >> 5, cj = (c & 31) * 8;
        *(v8us*)(Kg + kbase + (long)bb * 256 + cj) = *(const v8us*)&KbT[bb][cj];
    }
    if (t < 64) {
        float mu = mup[0][t] + mup[1][t] + mup[2][t] + mup[3][t];
        out[(long)pair * 1024 + bt * 64 + t] = mu;
    }
}

// MFMA q kernel, 128-wide b-tiles: 1D grid, pair = idx&127 (XCD L2 locality for G)
#define KT2 264
__global__ __launch_bounds__(256) void k_kb4(const ushort_t* __restrict__ Kg,
                                             const ushort_t* __restrict__ Ghi,
                                             const ushort_t* __restrict__ Glo,
                                             const float* __restrict__ SF2, float* __restrict__ out) {
    int pair = blockIdx.x & 127;
    int bt = blockIdx.x >> 7;
    int h = pair >> 5;
    int t = threadIdx.x;
    int w = t >> 6;
    int lane = t & 63;
    int l31 = lane & 31, lhalf = lane >> 5;

    __shared__ __align__(16) ushort_t KbT[128][KT2];
    __shared__ float qpart[4][128];

    float sf2 = SF2[h];
    long kbase = ((long)pair * 1024 + bt * 128) * 256;
#pragma unroll
    for (int e = 0; e < 16; e++) {
        int c = e * 256 + t;
        int bb = c >> 5, cj = (c & 31) * 8;
        *(v8us*)&KbT[bb][cj] = *(const v8us*)(Kg + kbase + (long)bb * 256 + cj);
    }
    __syncthreads();

    v16f acc[2][4];
#pragma unroll
    for (int mt = 0; mt < 2; mt++)
#pragma unroll
        for (int nt = 0; nt < 4; nt++)
#pragma unroll
            for (int r = 0; r < 16; r++) acc[mt][nt][r] = 0.f;

    const ushort_t* GhiP = Ghi + (long)pair * 65536;
    const ushort_t* GloP = Glo + (long)pair * 65536;
#pragma unroll 2
    for (int k0 = 0; k0 < 256; k0 += 16) {
        v8bf bfr[4];
#pragma unroll
        for (int nt = 0; nt < 4; nt++)
            bfr[nt] = *(const v8bf*)&KbT[nt * 32 + l31][k0 + lhalf * 8];
#pragma unroll
        for (int mt = 0; mt < 2; mt++) {
            int i = w * 64 + mt * 32 + l31;
            v8bf ah = *(const v8bf*)(GhiP + (long)i * 256 + k0 + lhalf * 8);
            v8bf al = *(const v8bf*)(GloP + (long)i * 256 + k0 + lhalf * 8);
#pragma unroll
            for (int nt = 0; nt < 4; nt++) {
                acc[mt][nt] = __builtin_amdgcn_mfma_f32_32x32x16_bf16(ah, bfr[nt], acc[mt][nt], 0, 0, 0);
                acc[mt][nt] = __builtin_amdgcn_mfma_f32_32x32x16_bf16(al, bfr[nt], acc[mt][nt], 0, 0, 0);
            }
        }
    }

    float qp[4] = {0.f, 0.f, 0.f, 0.f};
#pragma unroll
    for (int mt = 0; mt < 2; mt++) {
#pragma unroll
        for (int nt = 0; nt < 4; nt++) {
            int b = nt * 32 + l31;
#pragma unroll
            for (int g = 0; g < 4; g++) {
                int ibase = w * 64 + mt * 32 + 8 * g + 4 * lhalf;
                v4us k4 = *(const v4us*)&KbT[b][ibase];
#pragma unroll
                for (int e = 0; e < 4; e++) {
                    float kv = bf2f(k4[e]);
                    qp[nt] += kv * acc[mt][nt][4 * g + e];
                }
            }
        }
    }
#pragma unroll
    for (int nt = 0; nt < 4; nt++) {
        qp[nt] += __shfl_down(qp[nt], 32, 64);
        if (lhalf == 0) qpart[w][nt * 32 + l31] = qp[nt];
    }
    __syncthreads();

    if (t < 128) {
        float q = qpart[0][t] + qpart[1][t] + qpart[2][t] + qpart[3][t];
        out[(long)H_ * O_ * B_ + (long)pair * 1024 + bt * 128 + t] = sf2 - q;
    }
}

// ---------------------------------------------------------------------------
extern "C" void kernel_launch(void* const* d_in, const int* in_sizes, int n_in,
                              void* d_out, int out_size, void* d_ws, size_t ws_size,
                              hipStream_t stream) {
    const float* x = (const float*)d_in[0];
    const float* z = (const float*)d_in[1];
    const float* u_mean = (const float*)d_in[2];
    const float* u_tril_vec = (const float*)d_in[3];
    const float* m_old = (const float*)d_in[4];
    const float* L_old = (const float*)d_in[5];
    const float* z_old = (const float*)d_in[6];
    const float* theta = (const float*)d_in[7];

    const long BIGSZ = (long)HO * M2 * M2;  // 8388608
    const long MSZ = (long)HO * M_ * M_;    // 2097152

    float* ws = (float*)d_ws;
    long off = 0;
    float* BIG0 = ws + off; off += BIGSZ;  // KUU2 (+T1g in rows<64) -> AINV fp32
    float* BIG1 = ws + off; off += BIGSZ;  // LINVT h/l -> Y h/l -> Kg (part 1)
    float* BIG2 = ws + off; off += BIGSZ;  // Linv1|A1|Linv2|BLW -> AINV h/l -> Kg (part 2)
    float* BIG3 = ws + off; off += BIGSZ;  // WcT h/l -> G h/l
    float* ZS = ws + off; off += (long)HO * M2 * D_;
    float* XS = ws + off; off += (long)H_ * B_ * D_;
    float* ZN = ws + off; off += (long)HO * M2;
    float* XN = ws + off; off += (long)H_ * B_;
    float* MJ = ws + off; off += (long)HO * M2;
    float* CV = ws + off; off += (long)HO * M2;
    float* SF2v = ws + off; off += H_;

    float* KUU2 = BIG0;
    float* AINV = BIG0;
    float* T1g = BIG0;               // per-pair stride 65536, first 16384 floats
                                     // (KUU2 rows 0..63 — dead after a1a3)
    float* Linv1 = BIG2;
    float* A1 = BIG2 + MSZ;
    float* A3 = BIG2 + 2 * MSZ;
    float* Linv2 = BIG2 + 2 * MSZ;
    float* BLW = BIG2 + 3 * MSZ;
    ushort_t* LINVTh = (ushort_t*)BIG1;
    ushort_t* LINVTl = LINVTh + BIGSZ;
    ushort_t* AINVh = (ushort_t*)BIG2;
    ushort_t* AINVl = AINVh + BIGSZ;
    ushort_t* WcTh = (ushort_t*)BIG3;
    ushort_t* WcTl = WcTh + BIGSZ;
    ushort_t* Yh = (ushort_t*)BIG1;
    ushort_t* Yl = Yh + BIGSZ;
    ushort_t* Ghi = (ushort_t*)BIG3;
    ushort_t* Glo = Ghi + BIGSZ;
    ushort_t* Kg = (ushort_t*)BIG1;  // 64 MB spanning BIG1+BIG2
    const long BRoff = 128L * M2 + 128;

    // 1. preprocessing + kuu2 (fused)
    k_prekuu2<<<145, 256, 0, stream>>>(theta, x, z, z_old, SF2v, XS, XN, ZS, ZN, KUU2);
    // 2. chol TL + trinv -> Linv1 ; co: WcT part A (UT, zeros, L_old)
    k_choltri_tl<<<256, 256, 0, stream>>>(KUU2, Linv1, L_old, u_tril_vec, WcTh, WcTl);
    // 3. A1 = Linv1@kuf ; A3 = Linv1@L_old
    k_a1a3<<<dim3(HO, 2), 256, 0, stream>>>(Linv1, KUU2, L_old, A1, A3);
    // 4. BLW ; Schur ; m_joint + CV zero
    k_blwschur<<<dim3(HO, 3), 256, 0, stream>>>(A1, A3, BLW, KUU2, Linv1, m_old, u_mean, MJ, CV);
    // 5. chol BR -> Linv2 ; co: T1 = A1^T Linv1 -> T1g, LINVT zeros+Linv1 part, WcT BLW part
    k_choltri_br<<<512, 256, 0, stream>>>(KUU2 + BRoff, Linv2, A1, Linv1, T1g, BLW,
                                          LINVTh, LINVTl, WcTh, WcTl);
    // 6. BLi = -Linv2 @ T1g -> LINVT BLi part (transposed planes) + Linv2 part
    k_blicalc2<<<HO, 256, 0, stream>>>(Linv2, T1g, LINVTh, LINVTl);
    // 7. AINV = LINVT (.) LINVT -> fp32 (BIG0; KUU2/T1g dead) + planes (BIG2) + CV fused
    k_bmmx<1><<<dim3(HO, 3), 256, 0, stream>>>(LINVTh, LINVTl, LINVTh, LINVTl,
                                               AINV, AINVh, AINVl, nullptr, 1, 1.f, MJ, CV);
    // 8. Y = AINV @ Wc -> Y planes (BIG1; LINVT dead)
    k_bmmx<0><<<dim3(HO, 4), 256, 0, stream>>>(AINVh, AINVl, WcTh, WcTl,
                                               nullptr, Yh, Yl, nullptr, 2, 1.f, nullptr, nullptr);
    // 9. G = AINV - Y Y^T -> G planes (BIG3; WcT dead)
    k_bmmx<1><<<dim3(HO, 3), 256, 0, stream>>>(Yh, Yl, Yh, Yl,
                                               nullptr, Ghi, Glo, AINV, 0, -1.f, nullptr, nullptr);
    // 10. K build + mu (Kg over BIG1+BIG2 — Y and AINV planes dead)
    k_kbuild<<<dim3(16, HO), 256, 0, stream>>>(ZS, ZN, XS, XN, SF2v, CV, Kg, (float*)d_out);
    // 11. MFMA q/var
    k_kb4<<<1024, 256, 0, stream>>>(Kg, Ghi, Glo, SF2v, (float*)d_out);
}